// Round 1
// baseline (938.021 us; speedup 1.0000x reference)
//
#include <hip/hip_runtime.h>
#include <math.h>

// ---------------------------------------------------------------------------
// GCN link prediction:
//   deg_out/deg_in -> h1 = relu(Agg(x*rout @ W1)*rin + b1)
//   h  = Agg(h1*rout @ W2)*rin + b2
//   ab = h @ [Wp1_top | Wp1_bot]   (per-node predictor precompute)
//   per edge: z1 = relu(ab[s][0:64]+ab[d][64:128]+bp1); z2 = relu(z1@Wp2+bp2)
//             out = sigmoid(z2@Wp3 + bp3)
// CSR-by-dst built on device every launch (ws is re-poisoned each call).
// ---------------------------------------------------------------------------

__global__ void k_deg(const int* __restrict__ src, const int* __restrict__ dst,
                      int* __restrict__ cout_, int* __restrict__ cin_, int E) {
  int i = blockIdx.x * blockDim.x + threadIdx.x;
  if (i < E) {
    atomicAdd(&cout_[src[i]], 1);
    atomicAdd(&cin_[dst[i]], 1);
  }
}

// 1024 elements per block -> block sums
__global__ void k_scan1(const int* __restrict__ cnt, int* __restrict__ bsum, int N) {
  __shared__ int lds[256];
  int b = blockIdx.x, t = threadIdx.x;
  int base = b * 1024 + t * 4;
  int s = 0;
#pragma unroll
  for (int j = 0; j < 4; j++) if (base + j < N) s += cnt[base + j];
  lds[t] = s; __syncthreads();
  for (int st = 128; st > 0; st >>= 1) {
    if (t < st) lds[t] += lds[t + st];
    __syncthreads();
  }
  if (t == 0) bsum[b] = lds[0];
}

// exclusive scan of <=128 block sums, single block of 128 threads
__global__ void k_scan2(int* __restrict__ bsum, int nb) {
  __shared__ int lds[128];
  int t = threadIdx.x;
  int v = (t < nb) ? bsum[t] : 0;
  lds[t] = v; __syncthreads();
  for (int st = 1; st < 128; st <<= 1) {
    int add = (t >= st) ? lds[t - st] : 0;
    __syncthreads();
    lds[t] += add;
    __syncthreads();
  }
  if (t < nb) bsum[t] = lds[t] - v;  // exclusive
}

// per-element exclusive prefix -> row_start + cursor copy
__global__ void k_scan3(const int* __restrict__ cnt, const int* __restrict__ bsum,
                        int* __restrict__ rowst, int* __restrict__ cursor, int N) {
  __shared__ int lds[256];
  int b = blockIdx.x, t = threadIdx.x;
  int base = b * 1024 + t * 4;
  int v[4]; int s = 0;
#pragma unroll
  for (int j = 0; j < 4; j++) { v[j] = (base + j < N) ? cnt[base + j] : 0; s += v[j]; }
  lds[t] = s; __syncthreads();
  int mine = s;
  for (int st = 1; st < 256; st <<= 1) {
    int add = (t >= st) ? lds[t - st] : 0;
    __syncthreads();
    lds[t] += add;
    __syncthreads();
  }
  int excl = lds[t] - mine + bsum[b];
#pragma unroll
  for (int j = 0; j < 4; j++) {
    if (base + j < N) { rowst[base + j] = excl; cursor[base + j] = excl; excl += v[j]; }
  }
}

__global__ void k_fill(const int* __restrict__ src, const int* __restrict__ dst,
                       int* __restrict__ cursor, int* __restrict__ adj, int E) {
  int i = blockIdx.x * blockDim.x + threadIdx.x;
  if (i < E) {
    int pos = atomicAdd(&cursor[dst[i]], 1);
    adj[pos] = src[i];
  }
}

__global__ void k_rnorm(const int* __restrict__ cin_, const int* __restrict__ cout_,
                        float* __restrict__ rin, float* __restrict__ rout, int N) {
  int i = blockIdx.x * blockDim.x + threadIdx.x;
  if (i < N) {
    rin[i]  = rsqrtf((float)max(cin_[i], 1));
    rout[i] = rsqrtf((float)max(cout_[i], 1));
  }
}

// Wc[k][c] : c<64 -> Wp1[k][c] ; c>=64 -> Wp1[64+k][c-64]   (k<64, Wp1 is [128,64])
__global__ void k_build_wc(const float* __restrict__ Wp1, float* __restrict__ Wc) {
  int i = blockIdx.x * blockDim.x + threadIdx.x;
  if (i < 64 * 128) {
    int k = i >> 7, c = i & 127;
    Wc[i] = (c < 64) ? Wp1[k * 64 + c] : Wp1[(k + 64) * 64 + (c - 64)];
  }
}

// C[M,BN] = (A[M,K] * scale[M]?) @ W[K,BN].  8x4 register tile / thread.
template <int K, int BN>
__global__ __launch_bounds__(256) void k_gemm(
    const float* __restrict__ A, const float* __restrict__ scale,
    const float* __restrict__ W, float* __restrict__ C, int M) {
  constexpr int TM = 8, TN = 4;
  constexpr int NTX = BN / TN;       // 32 (BN=128) or 16 (BN=64)
  constexpr int NTY = 256 / NTX;     // 8 or 16
  constexpr int BM = NTY * TM;       // 64 or 128
  constexpr int KB = 16;
  constexpr int BMP = BM + 4;        // keeps rows 16B-aligned, 2-way-max banks

  __shared__ __attribute__((aligned(16))) float Ws[KB][BN];
  __shared__ __attribute__((aligned(16))) float As[KB][BMP];

  int tid = threadIdx.x;
  int row0 = blockIdx.x * BM;
  int tx = tid % NTX, ty = tid / NTX;

  float acc[TM][TN];
#pragma unroll
  for (int m = 0; m < TM; m++)
#pragma unroll
    for (int n = 0; n < TN; n++) acc[m][n] = 0.f;

  for (int k0 = 0; k0 < K; k0 += KB) {
    __syncthreads();
    // stage W chunk (contiguous rows k0..k0+KB-1)
    for (int idx = tid * 4; idx < KB * BN; idx += 256 * 4)
      *(float4*)&Ws[0][idx] = *(const float4*)&W[(size_t)k0 * BN + idx];
    // stage A chunk, transposed to [k][row], row-scaled
    for (int idx = tid; idx < BM * (KB / 4); idx += 256) {
      int r = idx >> 2;      // KB/4 == 4
      int kv = idx & 3;
      int row = row0 + r;
      float4 v = make_float4(0.f, 0.f, 0.f, 0.f);
      if (row < M) {
        v = *(const float4*)&A[(size_t)row * K + k0 + kv * 4];
        if (scale) { float sc = scale[row]; v.x *= sc; v.y *= sc; v.z *= sc; v.w *= sc; }
      }
      As[kv * 4 + 0][r] = v.x;
      As[kv * 4 + 1][r] = v.y;
      As[kv * 4 + 2][r] = v.z;
      As[kv * 4 + 3][r] = v.w;
    }
    __syncthreads();
#pragma unroll
    for (int kk = 0; kk < KB; kk++) {
      float4 a0 = *(const float4*)&As[kk][ty * TM];
      float4 a1 = *(const float4*)&As[kk][ty * TM + 4];
      float4 b  = *(const float4*)&Ws[kk][tx * TN];
      float am[TM] = {a0.x, a0.y, a0.z, a0.w, a1.x, a1.y, a1.z, a1.w};
      float bn[TN] = {b.x, b.y, b.z, b.w};
#pragma unroll
      for (int m = 0; m < TM; m++)
#pragma unroll
        for (int n = 0; n < TN; n++)
          acc[m][n] = fmaf(am[m], bn[n], acc[m][n]);
    }
  }
#pragma unroll
  for (int m = 0; m < TM; m++) {
    int row = row0 + ty * TM + m;
    if (row < M) {
      float4 o = make_float4(acc[m][0], acc[m][1], acc[m][2], acc[m][3]);
      *(float4*)&C[(size_t)row * BN + tx * TN] = o;
    }
  }
}

// one wave per node; F=128 -> float2/lane, F=64 -> float/lane
template <int F>
__global__ __launch_bounds__(256) void k_agg(
    const float* __restrict__ hin, const int* __restrict__ rowst,
    const int* __restrict__ adj, const float* __restrict__ rin,
    const float* __restrict__ bias, float* __restrict__ hout,
    int N, int E, int do_relu) {
  int node = (blockIdx.x * 256 + threadIdx.x) >> 6;
  int lane = threadIdx.x & 63;
  if (node >= N) return;
  int start = rowst[node];
  int end = (node + 1 < N) ? rowst[node + 1] : E;
  if (F == 128) {
    float ax = 0.f, ay = 0.f;
    for (int i = start; i < end; i++) {
      int s = adj[i];
      float2 v = *(const float2*)&hin[(size_t)s * 128 + lane * 2];
      ax += v.x; ay += v.y;
    }
    float r = rin[node];
    float ox = fmaf(ax, r, bias[lane * 2]);
    float oy = fmaf(ay, r, bias[lane * 2 + 1]);
    if (do_relu) { ox = fmaxf(ox, 0.f); oy = fmaxf(oy, 0.f); }
    float2 o; o.x = ox; o.y = oy;
    *(float2*)&hout[(size_t)node * 128 + lane * 2] = o;
  } else {
    float a = 0.f;
    for (int i = start; i < end; i++) a += hin[(size_t)adj[i] * 64 + lane];
    float o = fmaf(a, rin[node], bias[lane]);
    if (do_relu) o = fmaxf(o, 0.f);
    hout[(size_t)node * 64 + lane] = o;
  }
}

// per-edge MLP: thread = edge. Wp2 transposed in LDS -> uniform b128 broadcasts.
__global__ __launch_bounds__(256) void k_edge(
    const float* __restrict__ ab, const int* __restrict__ src,
    const int* __restrict__ dst, const float* __restrict__ Wp2,
    const float* __restrict__ bp1, const float* __restrict__ bp2,
    const float* __restrict__ Wp3, const float* __restrict__ bp3,
    float* __restrict__ out, int E) {
  __shared__ __attribute__((aligned(16))) float w2t[32][68];  // [k][j], row 272B
  __shared__ float sb1[64];
  __shared__ float sb2[32];
  __shared__ float sw3[32];
  int t = threadIdx.x;
  for (int i = t; i < 2048; i += 256) {
    int j = i >> 5, k = i & 31;
    w2t[k][j] = Wp2[i];
  }
  if (t < 64) sb1[t] = bp1[t];
  if (t < 32) { sb2[t] = bp2[t]; sw3[t] = Wp3[t]; }
  __syncthreads();

  int e = blockIdx.x * 256 + t;
  if (e >= E) return;
  int s = src[e], d = dst[e];
  const float4* ap = (const float4*)&ab[(size_t)s * 128];
  const float4* bp = (const float4*)&ab[(size_t)d * 128 + 64];

  float z1[64];
#pragma unroll
  for (int q = 0; q < 16; q++) {
    float4 av = ap[q], bv = bp[q];
    z1[4 * q + 0] = fmaxf(av.x + bv.x + sb1[4 * q + 0], 0.f);
    z1[4 * q + 1] = fmaxf(av.y + bv.y + sb1[4 * q + 1], 0.f);
    z1[4 * q + 2] = fmaxf(av.z + bv.z + sb1[4 * q + 2], 0.f);
    z1[4 * q + 3] = fmaxf(av.w + bv.w + sb1[4 * q + 3], 0.f);
  }
  float score = bp3[0];
  for (int k = 0; k < 32; k++) {
    float acc = sb2[k];
    const float4* wr = (const float4*)&w2t[k][0];
#pragma unroll
    for (int q = 0; q < 16; q++) {
      float4 wv = wr[q];
      acc = fmaf(z1[4 * q + 0], wv.x, acc);
      acc = fmaf(z1[4 * q + 1], wv.y, acc);
      acc = fmaf(z1[4 * q + 2], wv.z, acc);
      acc = fmaf(z1[4 * q + 3], wv.w, acc);
    }
    score = fmaf(fmaxf(acc, 0.f), sw3[k], score);
  }
  out[e] = 1.0f / (1.0f + __expf(-score));
}

extern "C" void kernel_launch(void* const* d_in, const int* in_sizes, int n_in,
                              void* d_out, int out_size, void* d_ws, size_t ws_size,
                              hipStream_t stream) {
  const float* x   = (const float*)d_in[0];
  const int*   src = (const int*)d_in[1];
  const int*   dst = (const int*)d_in[2];
  const float* W1  = (const float*)d_in[3];
  const float* b1  = (const float*)d_in[4];
  const float* W2  = (const float*)d_in[5];
  const float* b2  = (const float*)d_in[6];
  const float* Wp1 = (const float*)d_in[7];
  const float* bp1 = (const float*)d_in[8];
  const float* Wp2 = (const float*)d_in[9];
  const float* bp2 = (const float*)d_in[10];
  const float* Wp3 = (const float*)d_in[11];
  const float* bp3 = (const float*)d_in[12];
  float* out = (float*)d_out;

  int N = in_sizes[0] / 128;
  int E = in_sizes[1];

  char* w = (char*)d_ws;
  float* bufA = (float*)w;  w += (size_t)N * 128 * sizeof(float);  // h0 -> h2pre -> ab
  float* bufB = (float*)w;  w += (size_t)N * 128 * sizeof(float);  // h1 -> h
  int* cin_   = (int*)w;    w += (size_t)N * sizeof(int);
  int* cout_  = (int*)w;    w += (size_t)N * sizeof(int);
  int* rowst  = (int*)w;    w += (size_t)N * sizeof(int);
  int* cursor = (int*)w;    w += (size_t)N * sizeof(int);
  int* adj    = (int*)w;    w += (size_t)E * sizeof(int);
  int* bsum   = (int*)w;    w += 128 * sizeof(int);
  float* rin  = (float*)w;  w += (size_t)N * sizeof(float);
  float* rout = (float*)w;  w += (size_t)N * sizeof(float);
  float* Wc   = (float*)w;  w += (size_t)64 * 128 * sizeof(float);

  // cin_ and cout_ are adjacent -> single memset
  hipMemsetAsync(cin_, 0, (size_t)2 * N * sizeof(int), stream);

  int nb = (N + 1023) / 1024;  // <= 128 for N <= 131072
  k_deg<<<(E + 255) / 256, 256, 0, stream>>>(src, dst, cout_, cin_, E);
  k_scan1<<<nb, 256, 0, stream>>>(cin_, bsum, N);
  k_scan2<<<1, 128, 0, stream>>>(bsum, nb);
  k_scan3<<<nb, 256, 0, stream>>>(cin_, bsum, rowst, cursor, N);
  k_fill<<<(E + 255) / 256, 256, 0, stream>>>(src, dst, cursor, adj, E);
  k_rnorm<<<(N + 255) / 256, 256, 0, stream>>>(cin_, cout_, rin, rout, N);
  k_build_wc<<<32, 256, 0, stream>>>(Wp1, Wc);

  // layer 1: h0 = (x*rout) @ W1 -> bufA [N,128]
  k_gemm<128, 128><<<(N + 63) / 64, 256, 0, stream>>>(x, rout, W1, bufA, N);
  // agg1 + bias + relu -> bufB [N,128]
  k_agg<128><<<(N + 3) / 4, 256, 0, stream>>>(bufA, rowst, adj, rin, b1, bufB, N, E, 1);
  // layer 2: h2pre = (h1*rout) @ W2 -> bufA [N,64]
  k_gemm<128, 64><<<(N + 127) / 128, 256, 0, stream>>>(bufB, rout, W2, bufA, N);
  // agg2 + bias -> bufB [N,64]
  k_agg<64><<<(N + 3) / 4, 256, 0, stream>>>(bufA, rowst, adj, rin, b2, bufB, N, E, 0);
  // predictor precompute: ab = h @ Wc -> bufA [N,128]
  k_gemm<64, 128><<<(N + 63) / 64, 256, 0, stream>>>(bufB, nullptr, Wc, bufA, N);
  // edge MLP + sigmoid -> out [E]
  k_edge<<<(E + 255) / 256, 256, 0, stream>>>(bufA, src, dst, Wp2, bp1, bp2, Wp3, bp3, out, E);
}

// Round 2
// 865.750 us; speedup vs baseline: 1.0835x; 1.0835x over previous
//
#include <hip/hip_runtime.h>
#include <math.h>

// ---------------------------------------------------------------------------
// GCN link prediction:
//   deg_out/deg_in -> h1 = relu(Agg(x*rout @ W1)*rin + b1)
//   h  = Agg(h1*rout @ W2)*rin + b2
//   ab = h @ [Wp1_top | Wp1_bot]   (per-node predictor precompute)
//   per edge: z1 = relu(ab[s][0:64]+ab[d][64:128]+bp1); z2 = relu(z1@Wp2+bp2)
//             out = sigmoid(z2@Wp3 + bp3)
// CSR-by-dst built on device every launch (ws is re-poisoned each call).
// ---------------------------------------------------------------------------

__global__ void k_deg(const int* __restrict__ src, const int* __restrict__ dst,
                      int* __restrict__ cout_, int* __restrict__ cin_, int E) {
  int i = blockIdx.x * blockDim.x + threadIdx.x;
  if (i < E) {
    atomicAdd(&cout_[src[i]], 1);
    atomicAdd(&cin_[dst[i]], 1);
  }
}

// 1024 elements per block -> block sums
__global__ void k_scan1(const int* __restrict__ cnt, int* __restrict__ bsum, int N) {
  __shared__ int lds[256];
  int b = blockIdx.x, t = threadIdx.x;
  int base = b * 1024 + t * 4;
  int s = 0;
#pragma unroll
  for (int j = 0; j < 4; j++) if (base + j < N) s += cnt[base + j];
  lds[t] = s; __syncthreads();
  for (int st = 128; st > 0; st >>= 1) {
    if (t < st) lds[t] += lds[t + st];
    __syncthreads();
  }
  if (t == 0) bsum[b] = lds[0];
}

// exclusive scan of <=128 block sums, single block of 128 threads
__global__ void k_scan2(int* __restrict__ bsum, int nb) {
  __shared__ int lds[128];
  int t = threadIdx.x;
  int v = (t < nb) ? bsum[t] : 0;
  lds[t] = v; __syncthreads();
  for (int st = 1; st < 128; st <<= 1) {
    int add = (t >= st) ? lds[t - st] : 0;
    __syncthreads();
    lds[t] += add;
    __syncthreads();
  }
  if (t < nb) bsum[t] = lds[t] - v;  // exclusive
}

// per-element exclusive prefix -> row_start + cursor copy
__global__ void k_scan3(const int* __restrict__ cnt, const int* __restrict__ bsum,
                        int* __restrict__ rowst, int* __restrict__ cursor, int N) {
  __shared__ int lds[256];
  int b = blockIdx.x, t = threadIdx.x;
  int base = b * 1024 + t * 4;
  int v[4]; int s = 0;
#pragma unroll
  for (int j = 0; j < 4; j++) { v[j] = (base + j < N) ? cnt[base + j] : 0; s += v[j]; }
  lds[t] = s; __syncthreads();
  int mine = s;
  for (int st = 1; st < 256; st <<= 1) {
    int add = (t >= st) ? lds[t - st] : 0;
    __syncthreads();
    lds[t] += add;
    __syncthreads();
  }
  int excl = lds[t] - mine + bsum[b];
#pragma unroll
  for (int j = 0; j < 4; j++) {
    if (base + j < N) { rowst[base + j] = excl; cursor[base + j] = excl; excl += v[j]; }
  }
}

__global__ void k_fill(const int* __restrict__ src, const int* __restrict__ dst,
                       int* __restrict__ cursor, int* __restrict__ adj, int E) {
  int i = blockIdx.x * blockDim.x + threadIdx.x;
  if (i < E) {
    int pos = atomicAdd(&cursor[dst[i]], 1);
    adj[pos] = src[i];
  }
}

__global__ void k_rnorm(const int* __restrict__ cin_, const int* __restrict__ cout_,
                        float* __restrict__ rin, float* __restrict__ rout, int N) {
  int i = blockIdx.x * blockDim.x + threadIdx.x;
  if (i < N) {
    rin[i]  = rsqrtf((float)max(cin_[i], 1));
    rout[i] = rsqrtf((float)max(cout_[i], 1));
  }
}

// Wc[k][c] : c<64 -> Wp1[k][c] ; c>=64 -> Wp1[64+k][c-64]   (k<64, Wp1 is [128,64])
__global__ void k_build_wc(const float* __restrict__ Wp1, float* __restrict__ Wc) {
  int i = blockIdx.x * blockDim.x + threadIdx.x;
  if (i < 64 * 128) {
    int k = i >> 7, c = i & 127;
    Wc[i] = (c < 64) ? Wp1[k * 64 + c] : Wp1[(k + 64) * 64 + (c - 64)];
  }
}

// C[M,BN] = (A[M,K] * scale[M]?) @ W[K,BN].  8x4 register tile / thread.
template <int K, int BN>
__global__ __launch_bounds__(256) void k_gemm(
    const float* __restrict__ A, const float* __restrict__ scale,
    const float* __restrict__ W, float* __restrict__ C, int M) {
  constexpr int TM = 8, TN = 4;
  constexpr int NTX = BN / TN;       // 32 (BN=128) or 16 (BN=64)
  constexpr int NTY = 256 / NTX;     // 8 or 16
  constexpr int BM = NTY * TM;       // 64 or 128
  constexpr int KB = 16;
  constexpr int BMP = BM + 4;        // keeps rows 16B-aligned, 2-way-max banks

  __shared__ __attribute__((aligned(16))) float Ws[KB][BN];
  __shared__ __attribute__((aligned(16))) float As[KB][BMP];

  int tid = threadIdx.x;
  int row0 = blockIdx.x * BM;
  int tx = tid % NTX, ty = tid / NTX;

  float acc[TM][TN];
#pragma unroll
  for (int m = 0; m < TM; m++)
#pragma unroll
    for (int n = 0; n < TN; n++) acc[m][n] = 0.f;

  for (int k0 = 0; k0 < K; k0 += KB) {
    __syncthreads();
    // stage W chunk (contiguous rows k0..k0+KB-1)
    for (int idx = tid * 4; idx < KB * BN; idx += 256 * 4)
      *(float4*)&Ws[0][idx] = *(const float4*)&W[(size_t)k0 * BN + idx];
    // stage A chunk, transposed to [k][row], row-scaled
    for (int idx = tid; idx < BM * (KB / 4); idx += 256) {
      int r = idx >> 2;      // KB/4 == 4
      int kv = idx & 3;
      int row = row0 + r;
      float4 v = make_float4(0.f, 0.f, 0.f, 0.f);
      if (row < M) {
        v = *(const float4*)&A[(size_t)row * K + k0 + kv * 4];
        if (scale) { float sc = scale[row]; v.x *= sc; v.y *= sc; v.z *= sc; v.w *= sc; }
      }
      As[kv * 4 + 0][r] = v.x;
      As[kv * 4 + 1][r] = v.y;
      As[kv * 4 + 2][r] = v.z;
      As[kv * 4 + 3][r] = v.w;
    }
    __syncthreads();
#pragma unroll
    for (int kk = 0; kk < KB; kk++) {
      float4 a0 = *(const float4*)&As[kk][ty * TM];
      float4 a1 = *(const float4*)&As[kk][ty * TM + 4];
      float4 b  = *(const float4*)&Ws[kk][tx * TN];
      float am[TM] = {a0.x, a0.y, a0.z, a0.w, a1.x, a1.y, a1.z, a1.w};
      float bn[TN] = {b.x, b.y, b.z, b.w};
#pragma unroll
      for (int m = 0; m < TM; m++)
#pragma unroll
        for (int n = 0; n < TN; n++)
          acc[m][n] = fmaf(am[m], bn[n], acc[m][n]);
    }
  }
#pragma unroll
  for (int m = 0; m < TM; m++) {
    int row = row0 + ty * TM + m;
    if (row < M) {
      float4 o = make_float4(acc[m][0], acc[m][1], acc[m][2], acc[m][3]);
      *(float4*)&C[(size_t)row * BN + tx * TN] = o;
    }
  }
}

// one wave per node; F=128 -> float2/lane, F=64 -> float/lane. 2-deep ILP.
template <int F>
__global__ __launch_bounds__(256) void k_agg(
    const float* __restrict__ hin, const int* __restrict__ rowst,
    const int* __restrict__ adj, const float* __restrict__ rin,
    const float* __restrict__ bias, float* __restrict__ hout,
    int N, int E, int do_relu) {
  int node = (blockIdx.x * 256 + threadIdx.x) >> 6;
  int lane = threadIdx.x & 63;
  if (node >= N) return;
  int start = rowst[node];
  int end = (node + 1 < N) ? rowst[node + 1] : E;
  if (F == 128) {
    float ax0 = 0.f, ay0 = 0.f, ax1 = 0.f, ay1 = 0.f;
    int i = start;
    for (; i + 1 < end; i += 2) {
      int s0 = adj[i], s1 = adj[i + 1];
      float2 v0 = *(const float2*)&hin[(size_t)s0 * 128 + lane * 2];
      float2 v1 = *(const float2*)&hin[(size_t)s1 * 128 + lane * 2];
      ax0 += v0.x; ay0 += v0.y;
      ax1 += v1.x; ay1 += v1.y;
    }
    if (i < end) {
      float2 v = *(const float2*)&hin[(size_t)adj[i] * 128 + lane * 2];
      ax0 += v.x; ay0 += v.y;
    }
    float r = rin[node];
    float ox = fmaf(ax0 + ax1, r, bias[lane * 2]);
    float oy = fmaf(ay0 + ay1, r, bias[lane * 2 + 1]);
    if (do_relu) { ox = fmaxf(ox, 0.f); oy = fmaxf(oy, 0.f); }
    float2 o; o.x = ox; o.y = oy;
    *(float2*)&hout[(size_t)node * 128 + lane * 2] = o;
  } else {
    float a0 = 0.f, a1 = 0.f;
    int i = start;
    for (; i + 1 < end; i += 2) {
      float v0 = hin[(size_t)adj[i] * 64 + lane];
      float v1 = hin[(size_t)adj[i + 1] * 64 + lane];
      a0 += v0; a1 += v1;
    }
    if (i < end) a0 += hin[(size_t)adj[i] * 64 + lane];
    float o = fmaf(a0 + a1, rin[node], bias[lane]);
    if (do_relu) o = fmaxf(o, 0.f);
    hout[(size_t)node * 64 + lane] = o;
  }
}

// per-edge MLP as a blocked GEMM. Block = 256 threads, BM = 128 edges.
// Phase 1: z1 tile -> LDS [64][128] (j-major so phase 2 reads edge-quads b128).
// Phase 2: [128,64]@[64,32] with TM=4 x TN=4 register tile; weights amortized
//          over 4 edges per b128 read. Epilogue: relu, dot Wp3 via shfl_xor(8).
__global__ __launch_bounds__(256) void k_edge(
    const float* __restrict__ ab, const int* __restrict__ src,
    const int* __restrict__ dst, const float* __restrict__ Wp2,
    const float* __restrict__ bp1, const float* __restrict__ bp2,
    const float* __restrict__ Wp3, const float* __restrict__ bp3,
    float* __restrict__ out, int E) {
  __shared__ __attribute__((aligned(16))) float z1s[64][128];  // 32 KB
  __shared__ __attribute__((aligned(16))) float w2s[64][32];   // 8 KB, [j][k]
  __shared__ float sw3[32];

  int t = threadIdx.x;
  // stage Wp2 (row-major [64][32] == flat copy) + Wp3
  {
    const float4* wsrc = (const float4*)Wp2;
    float4* wdst = (float4*)w2s;
#pragma unroll
    for (int i = 0; i < 2; i++) wdst[t + 256 * i] = wsrc[t + 256 * i];
    if (t < 32) sw3[t] = Wp3[t];
  }

  int e0 = blockIdx.x * 128;
  // phase 1: 2 threads per edge (half = 32 j's each)
  {
    int m = t >> 1, half = t & 1;
    int e = e0 + m;
    int s = 0, d = 0;
    if (e < E) { s = src[e]; d = dst[e]; }
    const float4* apf = (const float4*)&ab[(size_t)s * 128] + half * 8;
    const float4* bpf = (const float4*)&ab[(size_t)d * 128 + 64] + half * 8;
    int jbase = half * 32;
#pragma unroll 4
    for (int q = 0; q < 8; q++) {
      float4 av = apf[q], bv = bpf[q];
      int j = jbase + 4 * q;
      z1s[j + 0][m] = fmaxf(av.x + bv.x + bp1[j + 0], 0.f);
      z1s[j + 1][m] = fmaxf(av.y + bv.y + bp1[j + 1], 0.f);
      z1s[j + 2][m] = fmaxf(av.z + bv.z + bp1[j + 2], 0.f);
      z1s[j + 3][m] = fmaxf(av.w + bv.w + bp1[j + 3], 0.f);
    }
  }
  __syncthreads();

  // phase 2: GEMM [128,64] @ [64,32], TM=4 edges x TN=4 outputs per thread
  int tx = t & 7, ty = t >> 3;       // tx: n-group, ty: m-group
  int n0 = tx * 4, m0 = ty * 4;
  float acc[4][4];
  {
    const float4 bb = *(const float4*)&bp2[n0];
#pragma unroll
    for (int m = 0; m < 4; m++) {
      acc[m][0] = bb.x; acc[m][1] = bb.y; acc[m][2] = bb.z; acc[m][3] = bb.w;
    }
  }
#pragma unroll 8
  for (int j = 0; j < 64; j++) {
    float4 w = *(const float4*)&w2s[j][n0];
    float4 a = *(const float4*)&z1s[j][m0];
    float am[4] = {a.x, a.y, a.z, a.w};
    float wn[4] = {w.x, w.y, w.z, w.w};
#pragma unroll
    for (int m = 0; m < 4; m++)
#pragma unroll
      for (int n = 0; n < 4; n++)
        acc[m][n] = fmaf(am[m], wn[n], acc[m][n]);
  }

  // epilogue: relu -> dot Wp3 partials -> butterfly over the 8 tx lanes
  float4 w3v = *(const float4*)&sw3[n0];
  float p[4];
#pragma unroll
  for (int m = 0; m < 4; m++) {
    float s = 0.f;
    s = fmaf(fmaxf(acc[m][0], 0.f), w3v.x, s);
    s = fmaf(fmaxf(acc[m][1], 0.f), w3v.y, s);
    s = fmaf(fmaxf(acc[m][2], 0.f), w3v.z, s);
    s = fmaf(fmaxf(acc[m][3], 0.f), w3v.w, s);
    p[m] = s;
  }
#pragma unroll
  for (int off = 1; off < 8; off <<= 1) {
#pragma unroll
    for (int m = 0; m < 4; m++) p[m] += __shfl_xor(p[m], off, 64);
  }
  if (tx < 4) {
    float score = p[0];
#pragma unroll
    for (int m = 1; m < 4; m++) score = (tx == m) ? p[m] : score;
    score += bp3[0];
    int e = e0 + m0 + tx;
    if (e < E) out[e] = 1.0f / (1.0f + __expf(-score));
  }
}

extern "C" void kernel_launch(void* const* d_in, const int* in_sizes, int n_in,
                              void* d_out, int out_size, void* d_ws, size_t ws_size,
                              hipStream_t stream) {
  const float* x   = (const float*)d_in[0];
  const int*   src = (const int*)d_in[1];
  const int*   dst = (const int*)d_in[2];
  const float* W1  = (const float*)d_in[3];
  const float* b1  = (const float*)d_in[4];
  const float* W2  = (const float*)d_in[5];
  const float* b2  = (const float*)d_in[6];
  const float* Wp1 = (const float*)d_in[7];
  const float* bp1 = (const float*)d_in[8];
  const float* Wp2 = (const float*)d_in[9];
  const float* bp2 = (const float*)d_in[10];
  const float* Wp3 = (const float*)d_in[11];
  const float* bp3 = (const float*)d_in[12];
  float* out = (float*)d_out;

  int N = in_sizes[0] / 128;
  int E = in_sizes[1];

  char* w = (char*)d_ws;
  float* bufA = (float*)w;  w += (size_t)N * 128 * sizeof(float);  // h0 -> h2pre -> ab
  float* bufB = (float*)w;  w += (size_t)N * 128 * sizeof(float);  // h1 -> h
  int* cin_   = (int*)w;    w += (size_t)N * sizeof(int);
  int* cout_  = (int*)w;    w += (size_t)N * sizeof(int);
  int* rowst  = (int*)w;    w += (size_t)N * sizeof(int);
  int* cursor = (int*)w;    w += (size_t)N * sizeof(int);
  int* adj    = (int*)w;    w += (size_t)E * sizeof(int);
  int* bsum   = (int*)w;    w += 128 * sizeof(int);
  float* rin  = (float*)w;  w += (size_t)N * sizeof(float);
  float* rout = (float*)w;  w += (size_t)N * sizeof(float);
  float* Wc   = (float*)w;  w += (size_t)64 * 128 * sizeof(float);

  // cin_ and cout_ are adjacent -> single memset
  hipMemsetAsync(cin_, 0, (size_t)2 * N * sizeof(int), stream);

  int nb = (N + 1023) / 1024;  // <= 128 for N <= 131072
  k_deg<<<(E + 255) / 256, 256, 0, stream>>>(src, dst, cout_, cin_, E);
  k_scan1<<<nb, 256, 0, stream>>>(cin_, bsum, N);
  k_scan2<<<1, 128, 0, stream>>>(bsum, nb);
  k_scan3<<<nb, 256, 0, stream>>>(cin_, bsum, rowst, cursor, N);
  k_fill<<<(E + 255) / 256, 256, 0, stream>>>(src, dst, cursor, adj, E);
  k_rnorm<<<(N + 255) / 256, 256, 0, stream>>>(cin_, cout_, rin, rout, N);
  k_build_wc<<<32, 256, 0, stream>>>(Wp1, Wc);

  // layer 1: h0 = (x*rout) @ W1 -> bufA [N,128]
  k_gemm<128, 128><<<(N + 63) / 64, 256, 0, stream>>>(x, rout, W1, bufA, N);
  // agg1 + bias + relu -> bufB [N,128]
  k_agg<128><<<(N + 3) / 4, 256, 0, stream>>>(bufA, rowst, adj, rin, b1, bufB, N, E, 1);
  // layer 2: h2pre = (h1*rout) @ W2 -> bufA [N,64]
  k_gemm<128, 64><<<(N + 127) / 128, 256, 0, stream>>>(bufB, rout, W2, bufA, N);
  // agg2 + bias -> bufB [N,64]
  k_agg<64><<<(N + 3) / 4, 256, 0, stream>>>(bufA, rowst, adj, rin, b2, bufB, N, E, 0);
  // predictor precompute: ab = h @ Wc -> bufA [N,128]
  k_gemm<64, 128><<<(N + 63) / 64, 256, 0, stream>>>(bufB, nullptr, Wc, bufA, N);
  // edge MLP + sigmoid -> out [E]
  k_edge<<<(E + 127) / 128, 256, 0, stream>>>(bufA, src, dst, Wp2, bp1, bp2, Wp3, bp3, out, E);
}

// Round 3
// 731.806 us; speedup vs baseline: 1.2818x; 1.1830x over previous
//
#include <hip/hip_runtime.h>
#include <math.h>

// ---------------------------------------------------------------------------
// GCN link prediction, bf16 node-feature tables (fp32 accumulate everywhere):
//   deg -> h0=bf16((x*rout)@W1) -> h1=bf16(relu(Agg(h0)*rin+b1))
//   h2p=bf16((h1*rout)@W2) -> h=bf16(Agg(h2p)*rin+b2)
//   ab = bf16(h @ [Wp1_top|Wp1_bot])   (per-node predictor precompute)
//   edges processed in CSR-by-dst order (dst-side gather ~sequential):
//     z1 = relu(ab[s][0:64]+ab[d][64:128]+bp1); z2 = relu(z1@Wp2+bp2)
//     out[eid] = sigmoid(z2@Wp3 + bp3)
// Rationale: round-2 counters show k_edge (and by structure the aggs) are
// L2-miss gather-bound (396 MB fetch @2.1 TB/s). bf16 + CSR order halve/
// localize the gather bytes.
// ---------------------------------------------------------------------------

__device__ __forceinline__ float bl(unsigned u) { return __uint_as_float(u << 16); }
__device__ __forceinline__ float bh(unsigned u) { return __uint_as_float(u & 0xffff0000u); }
__device__ __forceinline__ unsigned short f2bf(float f) {
  unsigned u = __float_as_uint(f);
  return (unsigned short)((u + 0x7fffu + ((u >> 16) & 1u)) >> 16);
}
__device__ __forceinline__ unsigned packbf2(float a, float b) {
  return (unsigned)f2bf(a) | ((unsigned)f2bf(b) << 16);
}

__global__ void k_deg(const int* __restrict__ src, const int* __restrict__ dst,
                      int* __restrict__ cout_, int* __restrict__ cin_, int E) {
  int i = blockIdx.x * blockDim.x + threadIdx.x;
  if (i < E) {
    atomicAdd(&cout_[src[i]], 1);
    atomicAdd(&cin_[dst[i]], 1);
  }
}

__global__ void k_scan1(const int* __restrict__ cnt, int* __restrict__ bsum, int N) {
  __shared__ int lds[256];
  int b = blockIdx.x, t = threadIdx.x;
  int base = b * 1024 + t * 4;
  int s = 0;
#pragma unroll
  for (int j = 0; j < 4; j++) if (base + j < N) s += cnt[base + j];
  lds[t] = s; __syncthreads();
  for (int st = 128; st > 0; st >>= 1) {
    if (t < st) lds[t] += lds[t + st];
    __syncthreads();
  }
  if (t == 0) bsum[b] = lds[0];
}

__global__ void k_scan2(int* __restrict__ bsum, int nb) {
  __shared__ int lds[128];
  int t = threadIdx.x;
  int v = (t < nb) ? bsum[t] : 0;
  lds[t] = v; __syncthreads();
  for (int st = 1; st < 128; st <<= 1) {
    int add = (t >= st) ? lds[t - st] : 0;
    __syncthreads();
    lds[t] += add;
    __syncthreads();
  }
  if (t < nb) bsum[t] = lds[t] - v;  // exclusive
}

__global__ void k_scan3(const int* __restrict__ cnt, const int* __restrict__ bsum,
                        int* __restrict__ rowst, int* __restrict__ cursor, int N) {
  __shared__ int lds[256];
  int b = blockIdx.x, t = threadIdx.x;
  int base = b * 1024 + t * 4;
  int v[4]; int s = 0;
#pragma unroll
  for (int j = 0; j < 4; j++) { v[j] = (base + j < N) ? cnt[base + j] : 0; s += v[j]; }
  lds[t] = s; __syncthreads();
  int mine = s;
  for (int st = 1; st < 256; st <<= 1) {
    int add = (t >= st) ? lds[t - st] : 0;
    __syncthreads();
    lds[t] += add;
    __syncthreads();
  }
  int excl = lds[t] - mine + bsum[b];
#pragma unroll
  for (int j = 0; j < 4; j++) {
    if (base + j < N) { rowst[base + j] = excl; cursor[base + j] = excl; excl += v[j]; }
  }
}

__global__ void k_fill(const int* __restrict__ src, const int* __restrict__ dst,
                       int* __restrict__ cursor, int* __restrict__ adj,
                       int* __restrict__ dnode, int* __restrict__ eidx, int E) {
  int i = blockIdx.x * blockDim.x + threadIdx.x;
  if (i < E) {
    int d = dst[i];
    int pos = atomicAdd(&cursor[d], 1);
    adj[pos] = src[i];
    dnode[pos] = d;
    eidx[pos] = i;
  }
}

__global__ void k_rnorm(const int* __restrict__ cin_, const int* __restrict__ cout_,
                        float* __restrict__ rin, float* __restrict__ rout, int N) {
  int i = blockIdx.x * blockDim.x + threadIdx.x;
  if (i < N) {
    rin[i]  = rsqrtf((float)max(cin_[i], 1));
    rout[i] = rsqrtf((float)max(cout_[i], 1));
  }
}

// Wc[k][c] : c<64 -> Wp1[k][c] ; c>=64 -> Wp1[64+k][c-64]   (k<64, Wp1 is [128,64])
__global__ void k_build_wc(const float* __restrict__ Wp1, float* __restrict__ Wc) {
  int i = blockIdx.x * blockDim.x + threadIdx.x;
  if (i < 64 * 128) {
    int k = i >> 7, c = i & 127;
    Wc[i] = (c < 64) ? Wp1[k * 64 + c] : Wp1[(k + 64) * 64 + (c - 64)];
  }
}

// C_bf16[M,BN] = (A[M,K] * scale[M]?) @ W[K,BN]. A fp32 or bf16. fp32 math.
template <int K, int BN, bool ABF>
__global__ __launch_bounds__(256) void k_gemm(
    const void* __restrict__ Av, const float* __restrict__ scale,
    const float* __restrict__ W, unsigned short* __restrict__ C, int M) {
  constexpr int TM = 8, TN = 4;
  constexpr int NTX = BN / TN;
  constexpr int NTY = 256 / NTX;
  constexpr int BM = NTY * TM;
  constexpr int KB = 16;
  constexpr int BMP = BM + 4;

  __shared__ __attribute__((aligned(16))) float Ws[KB][BN];
  __shared__ __attribute__((aligned(16))) float As[KB][BMP];

  int tid = threadIdx.x;
  int row0 = blockIdx.x * BM;
  int tx = tid % NTX, ty = tid / NTX;

  float acc[TM][TN];
#pragma unroll
  for (int m = 0; m < TM; m++)
#pragma unroll
    for (int n = 0; n < TN; n++) acc[m][n] = 0.f;

  for (int k0 = 0; k0 < K; k0 += KB) {
    __syncthreads();
    for (int idx = tid * 4; idx < KB * BN; idx += 256 * 4)
      *(float4*)&Ws[0][idx] = *(const float4*)&W[(size_t)k0 * BN + idx];
    for (int idx = tid; idx < BM * (KB / 4); idx += 256) {
      int r = idx >> 2;
      int kv = idx & 3;
      int row = row0 + r;
      float4 v = make_float4(0.f, 0.f, 0.f, 0.f);
      if (row < M) {
        if constexpr (ABF) {
          uint2 raw = *(const uint2*)((const unsigned short*)Av + (size_t)row * K + k0 + kv * 4);
          v = make_float4(bl(raw.x), bh(raw.x), bl(raw.y), bh(raw.y));
        } else {
          v = *(const float4*)((const float*)Av + (size_t)row * K + k0 + kv * 4);
        }
        if (scale) { float sc = scale[row]; v.x *= sc; v.y *= sc; v.z *= sc; v.w *= sc; }
      }
      As[kv * 4 + 0][r] = v.x;
      As[kv * 4 + 1][r] = v.y;
      As[kv * 4 + 2][r] = v.z;
      As[kv * 4 + 3][r] = v.w;
    }
    __syncthreads();
#pragma unroll
    for (int kk = 0; kk < KB; kk++) {
      float4 a0 = *(const float4*)&As[kk][ty * TM];
      float4 a1 = *(const float4*)&As[kk][ty * TM + 4];
      float4 b  = *(const float4*)&Ws[kk][tx * TN];
      float am[TM] = {a0.x, a0.y, a0.z, a0.w, a1.x, a1.y, a1.z, a1.w};
      float bn[TN] = {b.x, b.y, b.z, b.w};
#pragma unroll
      for (int m = 0; m < TM; m++)
#pragma unroll
        for (int n = 0; n < TN; n++)
          acc[m][n] = fmaf(am[m], bn[n], acc[m][n]);
    }
  }
#pragma unroll
  for (int m = 0; m < TM; m++) {
    int row = row0 + ty * TM + m;
    if (row < M) {
      uint2 o;
      o.x = packbf2(acc[m][0], acc[m][1]);
      o.y = packbf2(acc[m][2], acc[m][3]);
      *(uint2*)&C[(size_t)row * BN + tx * TN] = o;
    }
  }
}

// one wave per node; bf16 in/out, fp32 accumulate. 2-deep ILP.
template <int F>
__global__ __launch_bounds__(256) void k_agg(
    const unsigned short* __restrict__ hin, const int* __restrict__ rowst,
    const int* __restrict__ adj, const float* __restrict__ rin,
    const float* __restrict__ bias, unsigned short* __restrict__ hout,
    int N, int E, int do_relu) {
  int node = (blockIdx.x * 256 + threadIdx.x) >> 6;
  int lane = threadIdx.x & 63;
  if (node >= N) return;
  int start = rowst[node];
  int end = (node + 1 < N) ? rowst[node + 1] : E;
  if (F == 128) {
    const unsigned* h2 = (const unsigned*)hin;
    float ax0 = 0.f, ay0 = 0.f, ax1 = 0.f, ay1 = 0.f;
    int i = start;
    for (; i + 1 < end; i += 2) {
      unsigned w0 = h2[(size_t)adj[i] * 64 + lane];
      unsigned w1 = h2[(size_t)adj[i + 1] * 64 + lane];
      ax0 += bl(w0); ay0 += bh(w0);
      ax1 += bl(w1); ay1 += bh(w1);
    }
    if (i < end) {
      unsigned w0 = h2[(size_t)adj[i] * 64 + lane];
      ax0 += bl(w0); ay0 += bh(w0);
    }
    float r = rin[node];
    float ox = fmaf(ax0 + ax1, r, bias[lane * 2]);
    float oy = fmaf(ay0 + ay1, r, bias[lane * 2 + 1]);
    if (do_relu) { ox = fmaxf(ox, 0.f); oy = fmaxf(oy, 0.f); }
    ((unsigned*)hout)[(size_t)node * 64 + lane] = packbf2(ox, oy);
  } else {
    float a0 = 0.f, a1 = 0.f;
    int i = start;
    for (; i + 1 < end; i += 2) {
      unsigned short r0 = hin[(size_t)adj[i] * 64 + lane];
      unsigned short r1 = hin[(size_t)adj[i + 1] * 64 + lane];
      a0 += bl(r0); a1 += bl(r1);
    }
    if (i < end) a0 += bl(hin[(size_t)adj[i] * 64 + lane]);
    float o = fmaf(a0 + a1, rin[node], bias[lane]);
    if (do_relu) o = fmaxf(o, 0.f);
    hout[(size_t)node * 64 + lane] = f2bf(o);
  }
}

// per-edge MLP over CSR-ordered edge positions. Block = 128 edges.
// Phase 1: z1 tile -> LDS [64][128] from bf16 ab gathers (dst ~sequential).
// Phase 2: [128,64]@[64,32] reg-tiled; epilogue dot Wp3 + shfl butterfly,
// scatter to out[eid].
__global__ __launch_bounds__(256) void k_edge(
    const unsigned short* __restrict__ ab, const int* __restrict__ adj,
    const int* __restrict__ dnode, const int* __restrict__ eidx,
    const float* __restrict__ Wp2, const float* __restrict__ bp1,
    const float* __restrict__ bp2, const float* __restrict__ Wp3,
    const float* __restrict__ bp3, float* __restrict__ out, int E) {
  __shared__ __attribute__((aligned(16))) float z1s[64][128];  // 32 KB
  __shared__ __attribute__((aligned(16))) float w2s[64][32];   // 8 KB
  __shared__ float sw3[32];
  __shared__ float sb1[64];

  int t = threadIdx.x;
  {
    const float4* wsrc = (const float4*)Wp2;
    float4* wdst = (float4*)w2s;
#pragma unroll
    for (int i = 0; i < 2; i++) wdst[t + 256 * i] = wsrc[t + 256 * i];
    if (t < 32) sw3[t] = Wp3[t];
    if (t < 64) sb1[t] = bp1[t];
  }
  __syncthreads();

  int p0 = blockIdx.x * 128;
  {
    int m = t >> 1, half = t & 1, p = p0 + m;
    int s = 0, d = 0;
    if (p < E) { s = adj[p]; d = dnode[p]; }
    const uint4* apf = (const uint4*)(ab + (size_t)s * 128 + half * 32);
    const uint4* bpf = (const uint4*)(ab + (size_t)d * 128 + 64 + half * 32);
    int jbase = half * 32;
#pragma unroll
    for (int q = 0; q < 4; q++) {
      uint4 av = apf[q], bv = bpf[q];
      int j = jbase + 8 * q;
      z1s[j + 0][m] = fmaxf(bl(av.x) + bl(bv.x) + sb1[j + 0], 0.f);
      z1s[j + 1][m] = fmaxf(bh(av.x) + bh(bv.x) + sb1[j + 1], 0.f);
      z1s[j + 2][m] = fmaxf(bl(av.y) + bl(bv.y) + sb1[j + 2], 0.f);
      z1s[j + 3][m] = fmaxf(bh(av.y) + bh(bv.y) + sb1[j + 3], 0.f);
      z1s[j + 4][m] = fmaxf(bl(av.z) + bl(bv.z) + sb1[j + 4], 0.f);
      z1s[j + 5][m] = fmaxf(bh(av.z) + bh(bv.z) + sb1[j + 5], 0.f);
      z1s[j + 6][m] = fmaxf(bl(av.w) + bl(bv.w) + sb1[j + 6], 0.f);
      z1s[j + 7][m] = fmaxf(bh(av.w) + bh(bv.w) + sb1[j + 7], 0.f);
    }
  }
  __syncthreads();

  int tx = t & 7, ty = t >> 3;
  int n0 = tx * 4, m0 = ty * 4;
  float acc[4][4];
  {
    const float4 bb = *(const float4*)&bp2[n0];
#pragma unroll
    for (int m = 0; m < 4; m++) {
      acc[m][0] = bb.x; acc[m][1] = bb.y; acc[m][2] = bb.z; acc[m][3] = bb.w;
    }
  }
#pragma unroll 8
  for (int j = 0; j < 64; j++) {
    float4 w = *(const float4*)&w2s[j][n0];
    float4 a = *(const float4*)&z1s[j][m0];
    float am[4] = {a.x, a.y, a.z, a.w};
    float wn[4] = {w.x, w.y, w.z, w.w};
#pragma unroll
    for (int m = 0; m < 4; m++)
#pragma unroll
      for (int n = 0; n < 4; n++)
        acc[m][n] = fmaf(am[m], wn[n], acc[m][n]);
  }

  float4 w3v = *(const float4*)&sw3[n0];
  float p[4];
#pragma unroll
  for (int m = 0; m < 4; m++) {
    float s = 0.f;
    s = fmaf(fmaxf(acc[m][0], 0.f), w3v.x, s);
    s = fmaf(fmaxf(acc[m][1], 0.f), w3v.y, s);
    s = fmaf(fmaxf(acc[m][2], 0.f), w3v.z, s);
    s = fmaf(fmaxf(acc[m][3], 0.f), w3v.w, s);
    p[m] = s;
  }
#pragma unroll
  for (int off = 1; off < 8; off <<= 1) {
#pragma unroll
    for (int m = 0; m < 4; m++) p[m] += __shfl_xor(p[m], off, 64);
  }
  if (tx < 4) {
    float score = p[0];
#pragma unroll
    for (int m = 1; m < 4; m++) score = (tx == m) ? p[m] : score;
    score += bp3[0];
    int pp = p0 + m0 + tx;
    if (pp < E) out[eidx[pp]] = 1.0f / (1.0f + __expf(-score));
  }
}

extern "C" void kernel_launch(void* const* d_in, const int* in_sizes, int n_in,
                              void* d_out, int out_size, void* d_ws, size_t ws_size,
                              hipStream_t stream) {
  const float* x   = (const float*)d_in[0];
  const int*   src = (const int*)d_in[1];
  const int*   dst = (const int*)d_in[2];
  const float* W1  = (const float*)d_in[3];
  const float* b1  = (const float*)d_in[4];
  const float* W2  = (const float*)d_in[5];
  const float* b2  = (const float*)d_in[6];
  const float* Wp1 = (const float*)d_in[7];
  const float* bp1 = (const float*)d_in[8];
  const float* Wp2 = (const float*)d_in[9];
  const float* bp2 = (const float*)d_in[10];
  const float* Wp3 = (const float*)d_in[11];
  const float* bp3 = (const float*)d_in[12];
  float* out = (float*)d_out;

  int N = in_sizes[0] / 128;
  int E = in_sizes[1];

  char* w = (char*)d_ws;
  unsigned short* bufA = (unsigned short*)w; w += (size_t)N * 128 * 2;  // h0 -> h2pre -> ab
  unsigned short* bufB = (unsigned short*)w; w += (size_t)N * 128 * 2;  // h1 -> h
  int* cin_   = (int*)w;    w += (size_t)N * sizeof(int);
  int* cout_  = (int*)w;    w += (size_t)N * sizeof(int);
  int* rowst  = (int*)w;    w += (size_t)N * sizeof(int);
  int* cursor = (int*)w;    w += (size_t)N * sizeof(int);
  int* adj    = (int*)w;    w += (size_t)E * sizeof(int);
  int* dnode  = (int*)w;    w += (size_t)E * sizeof(int);
  int* eidx   = (int*)w;    w += (size_t)E * sizeof(int);
  int* bsum   = (int*)w;    w += 128 * sizeof(int);
  float* rin  = (float*)w;  w += (size_t)N * sizeof(float);
  float* rout = (float*)w;  w += (size_t)N * sizeof(float);
  float* Wc   = (float*)w;  w += (size_t)64 * 128 * sizeof(float);

  hipMemsetAsync(cin_, 0, (size_t)2 * N * sizeof(int), stream);

  int nb = (N + 1023) / 1024;
  k_deg<<<(E + 255) / 256, 256, 0, stream>>>(src, dst, cout_, cin_, E);
  k_scan1<<<nb, 256, 0, stream>>>(cin_, bsum, N);
  k_scan2<<<1, 128, 0, stream>>>(bsum, nb);
  k_scan3<<<nb, 256, 0, stream>>>(cin_, bsum, rowst, cursor, N);
  k_fill<<<(E + 255) / 256, 256, 0, stream>>>(src, dst, cursor, adj, dnode, eidx, E);
  k_rnorm<<<(N + 255) / 256, 256, 0, stream>>>(cin_, cout_, rin, rout, N);
  k_build_wc<<<32, 256, 0, stream>>>(Wp1, Wc);

  // layer 1: h0 = bf16((x*rout) @ W1) -> bufA [N,128]
  k_gemm<128, 128, false><<<(N + 63) / 64, 256, 0, stream>>>(x, rout, W1, bufA, N);
  // agg1 + bias + relu -> bufB [N,128] bf16
  k_agg<128><<<(N + 3) / 4, 256, 0, stream>>>(bufA, rowst, adj, rin, b1, bufB, N, E, 1);
  // layer 2: h2pre = bf16((h1*rout) @ W2) -> bufA [N,64]
  k_gemm<128, 64, true><<<(N + 127) / 128, 256, 0, stream>>>(bufB, rout, W2, bufA, N);
  // agg2 + bias -> bufB [N,64] bf16
  k_agg<64><<<(N + 3) / 4, 256, 0, stream>>>(bufA, rowst, adj, rin, b2, bufB, N, E, 0);
  // predictor precompute: ab = bf16(h @ Wc) -> bufA [N,128]
  k_gemm<64, 128, true><<<(N + 63) / 64, 256, 0, stream>>>(bufB, nullptr, Wc, bufA, N);
  // edge MLP + sigmoid, CSR order, scatter by eidx -> out [E]
  k_edge<<<(E + 127) / 128, 256, 0, stream>>>(bufA, adj, dnode, eidx, Wp2, bp1, bp2, Wp3, bp3, out, E);
}

// Round 4
// 584.232 us; speedup vs baseline: 1.6056x; 1.2526x over previous
//
#include <hip/hip_runtime.h>
#include <math.h>

// ---------------------------------------------------------------------------
// GCN link prediction, bf16 node tables, fp32 accumulate.
// CSR build is a fully atomic-free hierarchical counting sort:
//   k_hist  : per-block LDS histograms of 512 coarse buckets (node>>8),
//             for dst and src -> grams[2][512][256] (no atomics)
//   k_gscan*: exclusive scan of the 262144 gram counts (concatenated; dst
//             total == E so src region just carries +E offset)
//   k_part  : scatter edges into bucket regions via LDS cursors seeded from
//             the scan (no atomics). payload: (src, eid | dstlow<<21), src
//   k_dcsr  : per-bucket exact 256-bin LDS histogram + LDS scan ->
//             cin_, rowst, dst-sorted adj/dnode/eidx
//   k_scsr  : per-bucket histogram of src values -> cout_
// Rationale: round-3 counters show k_deg is pure scattered-atomic bound
// (WRITE_SIZE = 3.2M x 32B, 873 GB/s, VALU 0.3%); k_fill shares the
// pattern. Counting sort removes all 3.2M global atomics.
// Requires N <= 131072 (N = 100000 here).
// ---------------------------------------------------------------------------

#define NBLK 256
#define NBUK 512
#define GRD (NBUK * NBLK)          // 131072 per histogram
#define GRT (2 * GRD)              // 262144 total

__device__ __forceinline__ float bl(unsigned u) { return __uint_as_float(u << 16); }
__device__ __forceinline__ float bh(unsigned u) { return __uint_as_float(u & 0xffff0000u); }
__device__ __forceinline__ unsigned short f2bf(float f) {
  unsigned u = __float_as_uint(f);
  return (unsigned short)((u + 0x7fffu + ((u >> 16) & 1u)) >> 16);
}
__device__ __forceinline__ unsigned packbf2(float a, float b) {
  return (unsigned)f2bf(a) | ((unsigned)f2bf(b) << 16);
}

// ---- counting-sort CSR build -------------------------------------------------

__global__ __launch_bounds__(256) void k_hist(
    const int* __restrict__ src, const int* __restrict__ dst,
    int* __restrict__ grams, int E) {
  __shared__ int hd[NBUK], hs[NBUK];
  int blk = blockIdx.x, t = threadIdx.x;
  for (int k = t; k < NBUK; k += 256) { hd[k] = 0; hs[k] = 0; }
  __syncthreads();
  int chunk = (E + NBLK - 1) / NBLK;
  int start = blk * chunk, end = min(E, start + chunk);
  for (int i = start + t; i < end; i += 256) {
    atomicAdd(&hd[dst[i] >> 8], 1);
    atomicAdd(&hs[src[i] >> 8], 1);
  }
  __syncthreads();
  for (int k = t; k < NBUK; k += 256) {
    grams[k * NBLK + blk] = hd[k];
    grams[GRD + k * NBLK + blk] = hs[k];
  }
}

// scan stage 1: 256 blocks x 1024 elems -> bsum[256]
__global__ __launch_bounds__(256) void k_gscan1(const int* __restrict__ g,
                                                int* __restrict__ bsum) {
  __shared__ int lds[256];
  int b = blockIdx.x, t = threadIdx.x;
  int base = b * 1024 + t * 4;
  int s = g[base] + g[base + 1] + g[base + 2] + g[base + 3];
  lds[t] = s; __syncthreads();
  for (int st = 128; st > 0; st >>= 1) {
    if (t < st) lds[t] += lds[t + st];
    __syncthreads();
  }
  if (t == 0) bsum[b] = lds[0];
}

// scan stage 2: exclusive scan of 256 block sums in place
__global__ __launch_bounds__(256) void k_gscan2(int* __restrict__ bsum) {
  __shared__ int lds[256];
  int t = threadIdx.x;
  int v = bsum[t];
  lds[t] = v; __syncthreads();
  for (int st = 1; st < 256; st <<= 1) {
    int add = (t >= st) ? lds[t - st] : 0;
    __syncthreads();
    lds[t] += add;
    __syncthreads();
  }
  bsum[t] = lds[t] - v;
}

// scan stage 3: in-place exclusive prefix per element
__global__ __launch_bounds__(256) void k_gscan3(int* __restrict__ g,
                                                const int* __restrict__ bsum) {
  __shared__ int lds[256];
  int b = blockIdx.x, t = threadIdx.x;
  int base = b * 1024 + t * 4;
  int v[4]; int s = 0;
#pragma unroll
  for (int j = 0; j < 4; j++) { v[j] = g[base + j]; s += v[j]; }
  lds[t] = s; __syncthreads();
  int mine = s;
  for (int st = 1; st < 256; st <<= 1) {
    int add = (t >= st) ? lds[t - st] : 0;
    __syncthreads();
    lds[t] += add;
    __syncthreads();
  }
  int excl = lds[t] - mine + bsum[b];
#pragma unroll
  for (int j = 0; j < 4; j++) { g[base + j] = excl; excl += v[j]; }
}

// scatter into bucket regions via LDS cursors (no global atomics)
__global__ __launch_bounds__(256) void k_part(
    const int* __restrict__ src, const int* __restrict__ dst,
    const int* __restrict__ grams, uint2* __restrict__ pdst,
    int* __restrict__ sbuf, int E) {
  __shared__ int curd[NBUK], curs[NBUK];
  int blk = blockIdx.x, t = threadIdx.x;
  for (int k = t; k < NBUK; k += 256) {
    curd[k] = grams[k * NBLK + blk];
    curs[k] = grams[GRD + k * NBLK + blk] - E;
  }
  __syncthreads();
  int chunk = (E + NBLK - 1) / NBLK;
  int start = blk * chunk, end = min(E, start + chunk);
  for (int i = start + t; i < end; i += 256) {
    int s = src[i], d = dst[i];
    int pd = atomicAdd(&curd[d >> 8], 1);
    pdst[pd] = make_uint2((unsigned)s, (unsigned)i | ((unsigned)(d & 255) << 21));
    int ps = atomicAdd(&curs[s >> 8], 1);
    sbuf[ps] = s;
  }
}

// per-bucket exact CSR: cin_, rowst, dst-sorted adj/dnode/eidx
__global__ __launch_bounds__(256) void k_dcsr(
    const uint2* __restrict__ pdst, const int* __restrict__ grams,
    int* __restrict__ adj, int* __restrict__ dnode, int* __restrict__ eidx,
    int* __restrict__ rowst, int* __restrict__ cin_, int N) {
  __shared__ int hist[256], cur[256];
  int b = blockIdx.x, t = threadIdx.x;
  int base = grams[b * 256];
  int end  = grams[b * 256 + 256];
  hist[t] = 0; __syncthreads();
  for (int i = base + t; i < end; i += 256)
    atomicAdd(&hist[(pdst[i].y >> 21) & 255], 1);
  __syncthreads();
  int cnt = hist[t];
  for (int st = 1; st < 256; st <<= 1) {
    int add = (t >= st) ? hist[t - st] : 0;
    __syncthreads();
    hist[t] += add;
    __syncthreads();
  }
  int excl = hist[t] - cnt;
  cur[t] = excl;
  int node = b * 256 + t;
  if (node < N) { cin_[node] = cnt; rowst[node] = base + excl; }
  __syncthreads();
  for (int i = base + t; i < end; i += 256) {
    uint2 u = pdst[i];
    int lo = (u.y >> 21) & 255;
    int eid = (int)(u.y & 0x1FFFFFu);
    int pos = base + atomicAdd(&cur[lo], 1);
    adj[pos] = (int)u.x;
    dnode[pos] = b * 256 + lo;
    eidx[pos] = eid;
  }
}

// per-bucket histogram of src values -> cout_
__global__ __launch_bounds__(256) void k_scsr(
    const int* __restrict__ sbuf, const int* __restrict__ grams,
    int* __restrict__ cout_, int N, int E) {
  __shared__ int hist[256];
  int b = blockIdx.x, t = threadIdx.x;
  int base = grams[GRD + b * 256] - E;
  int end  = grams[GRD + b * 256 + 256] - E;
  hist[t] = 0; __syncthreads();
  for (int i = base + t; i < end; i += 256)
    atomicAdd(&hist[sbuf[i] & 255], 1);
  __syncthreads();
  int node = b * 256 + t;
  if (node < N) cout_[node] = hist[t];
}

__global__ void k_rnorm(const int* __restrict__ cin_, const int* __restrict__ cout_,
                        float* __restrict__ rin, float* __restrict__ rout, int N) {
  int i = blockIdx.x * blockDim.x + threadIdx.x;
  if (i < N) {
    rin[i]  = rsqrtf((float)max(cin_[i], 1));
    rout[i] = rsqrtf((float)max(cout_[i], 1));
  }
}

// Wc[k][c] : c<64 -> Wp1[k][c] ; c>=64 -> Wp1[64+k][c-64]   (k<64, Wp1 is [128,64])
__global__ void k_build_wc(const float* __restrict__ Wp1, float* __restrict__ Wc) {
  int i = blockIdx.x * blockDim.x + threadIdx.x;
  if (i < 64 * 128) {
    int k = i >> 7, c = i & 127;
    Wc[i] = (c < 64) ? Wp1[k * 64 + c] : Wp1[(k + 64) * 64 + (c - 64)];
  }
}

// ---- dense compute ----------------------------------------------------------

// C_bf16[M,BN] = (A[M,K] * scale[M]?) @ W[K,BN]. A fp32 or bf16. fp32 math.
template <int K, int BN, bool ABF>
__global__ __launch_bounds__(256) void k_gemm(
    const void* __restrict__ Av, const float* __restrict__ scale,
    const float* __restrict__ W, unsigned short* __restrict__ C, int M) {
  constexpr int TM = 8, TN = 4;
  constexpr int NTX = BN / TN;
  constexpr int NTY = 256 / NTX;
  constexpr int BM = NTY * TM;
  constexpr int KB = 16;
  constexpr int BMP = BM + 4;

  __shared__ __attribute__((aligned(16))) float Ws[KB][BN];
  __shared__ __attribute__((aligned(16))) float As[KB][BMP];

  int tid = threadIdx.x;
  int row0 = blockIdx.x * BM;
  int tx = tid % NTX, ty = tid / NTX;

  float acc[TM][TN];
#pragma unroll
  for (int m = 0; m < TM; m++)
#pragma unroll
    for (int n = 0; n < TN; n++) acc[m][n] = 0.f;

  for (int k0 = 0; k0 < K; k0 += KB) {
    __syncthreads();
    for (int idx = tid * 4; idx < KB * BN; idx += 256 * 4)
      *(float4*)&Ws[0][idx] = *(const float4*)&W[(size_t)k0 * BN + idx];
    for (int idx = tid; idx < BM * (KB / 4); idx += 256) {
      int r = idx >> 2;
      int kv = idx & 3;
      int row = row0 + r;
      float4 v = make_float4(0.f, 0.f, 0.f, 0.f);
      if (row < M) {
        if constexpr (ABF) {
          uint2 raw = *(const uint2*)((const unsigned short*)Av + (size_t)row * K + k0 + kv * 4);
          v = make_float4(bl(raw.x), bh(raw.x), bl(raw.y), bh(raw.y));
        } else {
          v = *(const float4*)((const float*)Av + (size_t)row * K + k0 + kv * 4);
        }
        if (scale) { float sc = scale[row]; v.x *= sc; v.y *= sc; v.z *= sc; v.w *= sc; }
      }
      As[kv * 4 + 0][r] = v.x;
      As[kv * 4 + 1][r] = v.y;
      As[kv * 4 + 2][r] = v.z;
      As[kv * 4 + 3][r] = v.w;
    }
    __syncthreads();
#pragma unroll
    for (int kk = 0; kk < KB; kk++) {
      float4 a0 = *(const float4*)&As[kk][ty * TM];
      float4 a1 = *(const float4*)&As[kk][ty * TM + 4];
      float4 b  = *(const float4*)&Ws[kk][tx * TN];
      float am[TM] = {a0.x, a0.y, a0.z, a0.w, a1.x, a1.y, a1.z, a1.w};
      float bn[TN] = {b.x, b.y, b.z, b.w};
#pragma unroll
      for (int m = 0; m < TM; m++)
#pragma unroll
        for (int n = 0; n < TN; n++)
          acc[m][n] = fmaf(am[m], bn[n], acc[m][n]);
    }
  }
#pragma unroll
  for (int m = 0; m < TM; m++) {
    int row = row0 + ty * TM + m;
    if (row < M) {
      uint2 o;
      o.x = packbf2(acc[m][0], acc[m][1]);
      o.y = packbf2(acc[m][2], acc[m][3]);
      *(uint2*)&C[(size_t)row * BN + tx * TN] = o;
    }
  }
}

// one wave per node; bf16 in/out, fp32 accumulate. 2-deep ILP.
template <int F>
__global__ __launch_bounds__(256) void k_agg(
    const unsigned short* __restrict__ hin, const int* __restrict__ rowst,
    const int* __restrict__ adj, const float* __restrict__ rin,
    const float* __restrict__ bias, unsigned short* __restrict__ hout,
    int N, int E, int do_relu) {
  int node = (blockIdx.x * 256 + threadIdx.x) >> 6;
  int lane = threadIdx.x & 63;
  if (node >= N) return;
  int start = rowst[node];
  int end = (node + 1 < N) ? rowst[node + 1] : E;
  if (F == 128) {
    const unsigned* h2 = (const unsigned*)hin;
    float ax0 = 0.f, ay0 = 0.f, ax1 = 0.f, ay1 = 0.f;
    int i = start;
    for (; i + 1 < end; i += 2) {
      unsigned w0 = h2[(size_t)adj[i] * 64 + lane];
      unsigned w1 = h2[(size_t)adj[i + 1] * 64 + lane];
      ax0 += bl(w0); ay0 += bh(w0);
      ax1 += bl(w1); ay1 += bh(w1);
    }
    if (i < end) {
      unsigned w0 = h2[(size_t)adj[i] * 64 + lane];
      ax0 += bl(w0); ay0 += bh(w0);
    }
    float r = rin[node];
    float ox = fmaf(ax0 + ax1, r, bias[lane * 2]);
    float oy = fmaf(ay0 + ay1, r, bias[lane * 2 + 1]);
    if (do_relu) { ox = fmaxf(ox, 0.f); oy = fmaxf(oy, 0.f); }
    ((unsigned*)hout)[(size_t)node * 64 + lane] = packbf2(ox, oy);
  } else {
    float a0 = 0.f, a1 = 0.f;
    int i = start;
    for (; i + 1 < end; i += 2) {
      unsigned short r0 = hin[(size_t)adj[i] * 64 + lane];
      unsigned short r1 = hin[(size_t)adj[i + 1] * 64 + lane];
      a0 += bl(r0); a1 += bl(r1);
    }
    if (i < end) a0 += bl(hin[(size_t)adj[i] * 64 + lane]);
    float o = fmaf(a0 + a1, rin[node], bias[lane]);
    if (do_relu) o = fmaxf(o, 0.f);
    hout[(size_t)node * 64 + lane] = f2bf(o);
  }
}

// per-edge MLP over CSR-ordered edge positions. Block = 128 edges.
__global__ __launch_bounds__(256) void k_edge(
    const unsigned short* __restrict__ ab, const int* __restrict__ adj,
    const int* __restrict__ dnode, const int* __restrict__ eidx,
    const float* __restrict__ Wp2, const float* __restrict__ bp1,
    const float* __restrict__ bp2, const float* __restrict__ Wp3,
    const float* __restrict__ bp3, float* __restrict__ out, int E) {
  __shared__ __attribute__((aligned(16))) float z1s[64][128];  // 32 KB
  __shared__ __attribute__((aligned(16))) float w2s[64][32];   // 8 KB
  __shared__ float sw3[32];
  __shared__ float sb1[64];

  int t = threadIdx.x;
  {
    const float4* wsrc = (const float4*)Wp2;
    float4* wdst = (float4*)w2s;
#pragma unroll
    for (int i = 0; i < 2; i++) wdst[t + 256 * i] = wsrc[t + 256 * i];
    if (t < 32) sw3[t] = Wp3[t];
    if (t < 64) sb1[t] = bp1[t];
  }
  __syncthreads();

  int p0 = blockIdx.x * 128;
  {
    int m = t >> 1, half = t & 1, p = p0 + m;
    int s = 0, d = 0;
    if (p < E) { s = adj[p]; d = dnode[p]; }
    const uint4* apf = (const uint4*)(ab + (size_t)s * 128 + half * 32);
    const uint4* bpf = (const uint4*)(ab + (size_t)d * 128 + 64 + half * 32);
    int jbase = half * 32;
#pragma unroll
    for (int q = 0; q < 4; q++) {
      uint4 av = apf[q], bv = bpf[q];
      int j = jbase + 8 * q;
      z1s[j + 0][m] = fmaxf(bl(av.x) + bl(bv.x) + sb1[j + 0], 0.f);
      z1s[j + 1][m] = fmaxf(bh(av.x) + bh(bv.x) + sb1[j + 1], 0.f);
      z1s[j + 2][m] = fmaxf(bl(av.y) + bl(bv.y) + sb1[j + 2], 0.f);
      z1s[j + 3][m] = fmaxf(bh(av.y) + bh(bv.y) + sb1[j + 3], 0.f);
      z1s[j + 4][m] = fmaxf(bl(av.z) + bl(bv.z) + sb1[j + 4], 0.f);
      z1s[j + 5][m] = fmaxf(bh(av.z) + bh(bv.z) + sb1[j + 5], 0.f);
      z1s[j + 6][m] = fmaxf(bl(av.w) + bl(bv.w) + sb1[j + 6], 0.f);
      z1s[j + 7][m] = fmaxf(bh(av.w) + bh(bv.w) + sb1[j + 7], 0.f);
    }
  }
  __syncthreads();

  int tx = t & 7, ty = t >> 3;
  int n0 = tx * 4, m0 = ty * 4;
  float acc[4][4];
  {
    const float4 bb = *(const float4*)&bp2[n0];
#pragma unroll
    for (int m = 0; m < 4; m++) {
      acc[m][0] = bb.x; acc[m][1] = bb.y; acc[m][2] = bb.z; acc[m][3] = bb.w;
    }
  }
#pragma unroll 8
  for (int j = 0; j < 64; j++) {
    float4 w = *(const float4*)&w2s[j][n0];
    float4 a = *(const float4*)&z1s[j][m0];
    float am[4] = {a.x, a.y, a.z, a.w};
    float wn[4] = {w.x, w.y, w.z, w.w};
#pragma unroll
    for (int m = 0; m < 4; m++)
#pragma unroll
      for (int n = 0; n < 4; n++)
        acc[m][n] = fmaf(am[m], wn[n], acc[m][n]);
  }

  float4 w3v = *(const float4*)&sw3[n0];
  float p[4];
#pragma unroll
  for (int m = 0; m < 4; m++) {
    float s = 0.f;
    s = fmaf(fmaxf(acc[m][0], 0.f), w3v.x, s);
    s = fmaf(fmaxf(acc[m][1], 0.f), w3v.y, s);
    s = fmaf(fmaxf(acc[m][2], 0.f), w3v.z, s);
    s = fmaf(fmaxf(acc[m][3], 0.f), w3v.w, s);
    p[m] = s;
  }
#pragma unroll
  for (int off = 1; off < 8; off <<= 1) {
#pragma unroll
    for (int m = 0; m < 4; m++) p[m] += __shfl_xor(p[m], off, 64);
  }
  if (tx < 4) {
    float score = p[0];
#pragma unroll
    for (int m = 1; m < 4; m++) score = (tx == m) ? p[m] : score;
    score += bp3[0];
    int pp = p0 + m0 + tx;
    if (pp < E) out[eidx[pp]] = 1.0f / (1.0f + __expf(-score));
  }
}

extern "C" void kernel_launch(void* const* d_in, const int* in_sizes, int n_in,
                              void* d_out, int out_size, void* d_ws, size_t ws_size,
                              hipStream_t stream) {
  const float* x   = (const float*)d_in[0];
  const int*   src = (const int*)d_in[1];
  const int*   dst = (const int*)d_in[2];
  const float* W1  = (const float*)d_in[3];
  const float* b1  = (const float*)d_in[4];
  const float* W2  = (const float*)d_in[5];
  const float* b2  = (const float*)d_in[6];
  const float* Wp1 = (const float*)d_in[7];
  const float* bp1 = (const float*)d_in[8];
  const float* Wp2 = (const float*)d_in[9];
  const float* bp2 = (const float*)d_in[10];
  const float* Wp3 = (const float*)d_in[11];
  const float* bp3 = (const float*)d_in[12];
  float* out = (float*)d_out;

  int N = in_sizes[0] / 128;
  int E = in_sizes[1];

  char* w = (char*)d_ws;
  // bufA aliases pdst+sbuf (both dead before the first GEMM writes bufA)
  unsigned short* bufA = (unsigned short*)w;           // [N,128] bf16 = 25.6 MB
  uint2* pdst = (uint2*)w;                             // E*8 = 12.8 MB (alias)
  int*   sbuf = (int*)(w + (size_t)E * 8);             // E*4 = 6.4 MB  (alias)
  w += (size_t)N * 128 * 2;
  unsigned short* bufB = (unsigned short*)w; w += (size_t)N * 128 * 2;
  int* grams  = (int*)w;    w += (size_t)GRT * sizeof(int);   // 1 MB
  int* bsum   = (int*)w;    w += 256 * sizeof(int);
  int* cin_   = (int*)w;    w += (size_t)N * sizeof(int);
  int* cout_  = (int*)w;    w += (size_t)N * sizeof(int);
  int* rowst  = (int*)w;    w += (size_t)N * sizeof(int);
  int* adj    = (int*)w;    w += (size_t)E * sizeof(int);
  int* dnode  = (int*)w;    w += (size_t)E * sizeof(int);
  int* eidx   = (int*)w;    w += (size_t)E * sizeof(int);
  float* rin  = (float*)w;  w += (size_t)N * sizeof(float);
  float* rout = (float*)w;  w += (size_t)N * sizeof(float);
  float* Wc   = (float*)w;  w += (size_t)64 * 128 * sizeof(float);

  int nbk = (N + 255) / 256;  // 391 node-buckets

  // ---- CSR build (atomic-free counting sort) ----
  k_hist<<<NBLK, 256, 0, stream>>>(src, dst, grams, E);
  k_gscan1<<<GRT / 1024, 256, 0, stream>>>(grams, bsum);
  k_gscan2<<<1, 256, 0, stream>>>(bsum);
  k_gscan3<<<GRT / 1024, 256, 0, stream>>>(grams, bsum);
  k_part<<<NBLK, 256, 0, stream>>>(src, dst, grams, pdst, sbuf, E);
  k_dcsr<<<nbk, 256, 0, stream>>>(pdst, grams, adj, dnode, eidx, rowst, cin_, N);
  k_scsr<<<nbk, 256, 0, stream>>>(sbuf, grams, cout_, N, E);
  k_rnorm<<<(N + 255) / 256, 256, 0, stream>>>(cin_, cout_, rin, rout, N);
  k_build_wc<<<32, 256, 0, stream>>>(Wp1, Wc);

  // ---- dense pipeline (pdst/sbuf dead from here; bufA reused) ----
  // layer 1: h0 = bf16((x*rout) @ W1) -> bufA [N,128]
  k_gemm<128, 128, false><<<(N + 63) / 64, 256, 0, stream>>>(x, rout, W1, bufA, N);
  // agg1 + bias + relu -> bufB [N,128] bf16
  k_agg<128><<<(N + 3) / 4, 256, 0, stream>>>(bufA, rowst, adj, rin, b1, bufB, N, E, 1);
  // layer 2: h2pre = bf16((h1*rout) @ W2) -> bufA [N,64]
  k_gemm<128, 64, true><<<(N + 127) / 128, 256, 0, stream>>>(bufB, rout, W2, bufA, N);
  // agg2 + bias -> bufB [N,64] bf16
  k_agg<64><<<(N + 3) / 4, 256, 0, stream>>>(bufA, rowst, adj, rin, b2, bufB, N, E, 0);
  // predictor precompute: ab = bf16(h @ Wc) -> bufA [N,128]
  k_gemm<64, 128, true><<<(N + 63) / 64, 256, 0, stream>>>(bufB, nullptr, Wc, bufA, N);
  // edge MLP + sigmoid, CSR order, scatter by eidx -> out [E]
  k_edge<<<(E + 127) / 128, 256, 0, stream>>>(bufA, adj, dnode, eidx, Wp2, bp1, bp2, Wp3, bp3, out, E);
}

// Round 5
// 489.594 us; speedup vs baseline: 1.9159x; 1.1933x over previous
//
#include <hip/hip_runtime.h>
#include <math.h>

// ---------------------------------------------------------------------------
// GCN link prediction. bf16 node tables + bf16 MFMA for all dense math,
// fp32 accumulate. Atomic-free counting-sort CSR build (round-4).
// Round-5 change: k_gemm and k_edge phase-2 use v_mfma_f32_16x16x32_bf16
// (round-4 counters: k_edge VALUBusy 71% = fp32-FMA bound; GEMMs same).
// MFMA layouts (m89-verified): a[j]=A[lane&15][quad*8+j], b[j]=B[quad*8+j][lane&15],
// d[reg]=D[quad*4+reg][lane&15]. Weights pre-transposed bf16 [N][K] (k_prep).
// ---------------------------------------------------------------------------

#define NBLK 256
#define NBUK 512
#define GRD (NBUK * NBLK)
#define GRT (2 * GRD)

typedef __attribute__((ext_vector_type(8))) short bf16x8;
typedef __attribute__((ext_vector_type(4))) float f32x4;

__device__ __forceinline__ float bl(unsigned u) { return __uint_as_float(u << 16); }
__device__ __forceinline__ float bh(unsigned u) { return __uint_as_float(u & 0xffff0000u); }
__device__ __forceinline__ unsigned short f2bf(float f) {
  unsigned u = __float_as_uint(f);
  return (unsigned short)((u + 0x7fffu + ((u >> 16) & 1u)) >> 16);
}
__device__ __forceinline__ unsigned packbf2(float a, float b) {
  return (unsigned)f2bf(a) | ((unsigned)f2bf(b) << 16);
}

// ---- counting-sort CSR build ------------------------------------------------

__global__ __launch_bounds__(256) void k_hist(
    const int* __restrict__ src, const int* __restrict__ dst,
    int* __restrict__ grams, int E) {
  __shared__ int hd[NBUK], hs[NBUK];
  int blk = blockIdx.x, t = threadIdx.x;
  for (int k = t; k < NBUK; k += 256) { hd[k] = 0; hs[k] = 0; }
  __syncthreads();
  int chunk = (E + NBLK - 1) / NBLK;
  int start = blk * chunk, end = min(E, start + chunk);
  for (int i = start + t; i < end; i += 256) {
    atomicAdd(&hd[dst[i] >> 8], 1);
    atomicAdd(&hs[src[i] >> 8], 1);
  }
  __syncthreads();
  for (int k = t; k < NBUK; k += 256) {
    grams[k * NBLK + blk] = hd[k];
    grams[GRD + k * NBLK + blk] = hs[k];
  }
}

__global__ __launch_bounds__(256) void k_gscan1(const int* __restrict__ g,
                                                int* __restrict__ bsum) {
  __shared__ int lds[256];
  int b = blockIdx.x, t = threadIdx.x;
  int base = b * 1024 + t * 4;
  int s = g[base] + g[base + 1] + g[base + 2] + g[base + 3];
  lds[t] = s; __syncthreads();
  for (int st = 128; st > 0; st >>= 1) {
    if (t < st) lds[t] += lds[t + st];
    __syncthreads();
  }
  if (t == 0) bsum[b] = lds[0];
}

// element exclusive scan; block prefix recomputed locally from bsum (fused)
__global__ __launch_bounds__(256) void k_gscan3(int* __restrict__ g,
                                                const int* __restrict__ bsum) {
  __shared__ int lds[256], lds2[256];
  int b = blockIdx.x, t = threadIdx.x;
  int bv = bsum[t];
  lds2[t] = bv; __syncthreads();
  for (int st = 1; st < 256; st <<= 1) {
    int add = (t >= st) ? lds2[t - st] : 0;
    __syncthreads();
    lds2[t] += add;
    __syncthreads();
  }
  int bpref = (b > 0) ? lds2[b - 1] : 0;

  int base = b * 1024 + t * 4;
  int v[4]; int s = 0;
#pragma unroll
  for (int j = 0; j < 4; j++) { v[j] = g[base + j]; s += v[j]; }
  lds[t] = s; __syncthreads();
  int mine = s;
  for (int st = 1; st < 256; st <<= 1) {
    int add = (t >= st) ? lds[t - st] : 0;
    __syncthreads();
    lds[t] += add;
    __syncthreads();
  }
  int excl = lds[t] - mine + bpref;
#pragma unroll
  for (int j = 0; j < 4; j++) { g[base + j] = excl; excl += v[j]; }
}

__global__ __launch_bounds__(256) void k_part(
    const int* __restrict__ src, const int* __restrict__ dst,
    const int* __restrict__ grams, uint2* __restrict__ pdst,
    int* __restrict__ sbuf, int E) {
  __shared__ int curd[NBUK], curs[NBUK];
  int blk = blockIdx.x, t = threadIdx.x;
  for (int k = t; k < NBUK; k += 256) {
    curd[k] = grams[k * NBLK + blk];
    curs[k] = grams[GRD + k * NBLK + blk] - E;
  }
  __syncthreads();
  int chunk = (E + NBLK - 1) / NBLK;
  int start = blk * chunk, end = min(E, start + chunk);
  for (int i = start + t; i < end; i += 256) {
    int s = src[i], d = dst[i];
    int pd = atomicAdd(&curd[d >> 8], 1);
    pdst[pd] = make_uint2((unsigned)s, (unsigned)i | ((unsigned)(d & 255) << 21));
    int ps = atomicAdd(&curs[s >> 8], 1);
    sbuf[ps] = s;
  }
}

// per-bucket exact CSR: rin (rsqrt in-deg), rowst, dst-sorted adj/dnode/eidx
__global__ __launch_bounds__(256) void k_dcsr(
    const uint2* __restrict__ pdst, const int* __restrict__ grams,
    int* __restrict__ adj, int* __restrict__ dnode, int* __restrict__ eidx,
    int* __restrict__ rowst, float* __restrict__ rin, int N) {
  __shared__ int hist[256], cur[256];
  int b = blockIdx.x, t = threadIdx.x;
  int base = grams[b * 256];
  int end  = grams[b * 256 + 256];
  hist[t] = 0; __syncthreads();
  for (int i = base + t; i < end; i += 256)
    atomicAdd(&hist[(pdst[i].y >> 21) & 255], 1);
  __syncthreads();
  int cnt = hist[t];
  for (int st = 1; st < 256; st <<= 1) {
    int add = (t >= st) ? hist[t - st] : 0;
    __syncthreads();
    hist[t] += add;
    __syncthreads();
  }
  int excl = hist[t] - cnt;
  cur[t] = excl;
  int node = b * 256 + t;
  if (node < N) {
    rowst[node] = base + excl;
    rin[node] = rsqrtf((float)max(cnt, 1));
  }
  __syncthreads();
  for (int i = base + t; i < end; i += 256) {
    uint2 u = pdst[i];
    int lo = (u.y >> 21) & 255;
    int eid = (int)(u.y & 0x1FFFFFu);
    int pos = base + atomicAdd(&cur[lo], 1);
    adj[pos] = (int)u.x;
    dnode[pos] = b * 256 + lo;
    eidx[pos] = eid;
  }
}

// per-bucket histogram of src values -> rout (rsqrt out-deg)
__global__ __launch_bounds__(256) void k_scsr(
    const int* __restrict__ sbuf, const int* __restrict__ grams,
    float* __restrict__ rout, int N, int E) {
  __shared__ int hist[256];
  int b = blockIdx.x, t = threadIdx.x;
  int base = grams[GRD + b * 256] - E;
  int end  = grams[GRD + b * 256 + 256] - E;
  hist[t] = 0; __syncthreads();
  for (int i = base + t; i < end; i += 256)
    atomicAdd(&hist[sbuf[i] & 255], 1);
  __syncthreads();
  int node = b * 256 + t;
  if (node < N) rout[node] = rsqrtf((float)max(hist[t], 1));
}

// bf16-transposed weights: W1t[128][128], W2t[64][128], Wct[128][64], Wp2t[32][64]
__global__ void k_prep(const float* __restrict__ W1, const float* __restrict__ W2,
                       const float* __restrict__ Wp1, const float* __restrict__ Wp2,
                       unsigned short* __restrict__ W1t, unsigned short* __restrict__ W2t,
                       unsigned short* __restrict__ Wct, unsigned short* __restrict__ Wp2t) {
  int i = blockIdx.x * 256 + threadIdx.x;
  if (i < 16384) {
    int n = i >> 7, k = i & 127;
    W1t[i] = f2bf(W1[k * 128 + n]);
  } else if (i < 24576) {
    int j = i - 16384; int n = j >> 7, k = j & 127;
    W2t[j] = f2bf(W2[k * 64 + n]);
  } else if (i < 32768) {
    int j = i - 24576; int c = j >> 6, k = j & 63;
    float v = (c < 64) ? Wp1[k * 64 + c] : Wp1[(k + 64) * 64 + (c - 64)];
    Wct[j] = f2bf(v);
  } else if (i < 34816) {
    int j = i - 32768; int n = j >> 6, k = j & 63;
    Wp2t[j] = f2bf(Wp2[k * 32 + n]);
  }
}

// ---- MFMA GEMM: C_bf16[M,BN] = (A[M,K]*scale[M]?) @ W[K,BN], Wt bf16 [BN][K]
template <int K, int BN, bool ABF, bool SC>
__global__ __launch_bounds__(256) void k_gemm(
    const void* __restrict__ Av, const float* __restrict__ scale,
    const unsigned short* __restrict__ Wt, unsigned short* __restrict__ C, int M) {
  constexpr int KP = K + 8;  // +16B pad: row stride 4 banks -> 2-way max (free)
  __shared__ __attribute__((aligned(16))) unsigned short As[64][KP];
  __shared__ __attribute__((aligned(16))) unsigned short Ws[BN][KP];
  int tid = threadIdx.x;
  int row0 = blockIdx.x * 64;

  // stage Wt (straight bf16 copy, padded rows)
  for (int i = tid; i < BN * K / 8; i += 256) {
    int n = i / (K / 8), seg = i % (K / 8);
    *(uint4*)&Ws[n][seg * 8] = ((const uint4*)Wt)[i];
  }
  // stage A: 4 threads/row, convert+scale+pack to bf16
  {
    constexpr int CH = K / 4;  // elems per thread
    int r = tid >> 2, q = tid & 3;
    int row = row0 + r;
    if (row < M) {
      float sc = SC ? scale[row] : 1.0f;
      if constexpr (!ABF) {
        const float4* ap = (const float4*)((const float*)Av + (size_t)row * K + q * CH);
#pragma unroll
        for (int c = 0; c < CH / 8; c++) {
          float4 v0 = ap[2 * c], v1 = ap[2 * c + 1];
          uint4 o;
          o.x = packbf2(v0.x * sc, v0.y * sc);
          o.y = packbf2(v0.z * sc, v0.w * sc);
          o.z = packbf2(v1.x * sc, v1.y * sc);
          o.w = packbf2(v1.z * sc, v1.w * sc);
          *(uint4*)&As[r][q * CH + c * 8] = o;
        }
      } else {
        const uint4* ap = (const uint4*)((const unsigned short*)Av + (size_t)row * K + q * CH);
#pragma unroll
        for (int c = 0; c < CH / 8; c++) {
          uint4 v = ap[c];
          if constexpr (SC) {
            uint4 o;
            o.x = packbf2(bl(v.x) * sc, bh(v.x) * sc);
            o.y = packbf2(bl(v.y) * sc, bh(v.y) * sc);
            o.z = packbf2(bl(v.z) * sc, bh(v.z) * sc);
            o.w = packbf2(bl(v.w) * sc, bh(v.w) * sc);
            *(uint4*)&As[r][q * CH + c * 8] = o;
          } else {
            *(uint4*)&As[r][q * CH + c * 8] = v;
          }
        }
      }
    } else {
#pragma unroll
      for (int c = 0; c < CH / 8; c++)
        *(uint4*)&As[r][q * CH + c * 8] = make_uint4(0, 0, 0, 0);
    }
  }
  __syncthreads();

  // compute: wave w -> rows [w*16, w*16+16), all BN cols
  constexpr int KS = K / 32;
  constexpr int NT = BN / 16;
  int wav = tid >> 6, lane = tid & 63;
  int quad = lane >> 4, lrow = lane & 15;
  int mb = wav * 16;

  bf16x8 af[KS];
#pragma unroll
  for (int s = 0; s < KS; s++)
    af[s] = *(const bf16x8*)&As[mb + lrow][s * 32 + quad * 8];

  f32x4 acc[NT];
#pragma unroll
  for (int nt = 0; nt < NT; nt++) acc[nt] = (f32x4){0.f, 0.f, 0.f, 0.f};
#pragma unroll
  for (int nt = 0; nt < NT; nt++) {
#pragma unroll
    for (int s = 0; s < KS; s++) {
      bf16x8 bf = *(const bf16x8*)&Ws[nt * 16 + lrow][s * 32 + quad * 8];
      acc[nt] = __builtin_amdgcn_mfma_f32_16x16x32_bf16(af[s], bf, acc[nt], 0, 0, 0);
    }
  }

  // writeback: d[reg] = D[quad*4+reg][lrow]
#pragma unroll
  for (int nt = 0; nt < NT; nt++) {
#pragma unroll
    for (int reg = 0; reg < 4; reg++) {
      int row = row0 + mb + quad * 4 + reg;
      if (row < M) C[(size_t)row * BN + nt * 16 + lrow] = f2bf(acc[nt][reg]);
    }
  }
}

// one wave per node; bf16 in/out, fp32 accumulate. 2-deep ILP.
template <int F>
__global__ __launch_bounds__(256) void k_agg(
    const unsigned short* __restrict__ hin, const int* __restrict__ rowst,
    const int* __restrict__ adj, const float* __restrict__ rin,
    const float* __restrict__ bias, unsigned short* __restrict__ hout,
    int N, int E, int do_relu) {
  int node = (blockIdx.x * 256 + threadIdx.x) >> 6;
  int lane = threadIdx.x & 63;
  if (node >= N) return;
  int start = rowst[node];
  int end = (node + 1 < N) ? rowst[node + 1] : E;
  if (F == 128) {
    const unsigned* h2 = (const unsigned*)hin;
    float ax0 = 0.f, ay0 = 0.f, ax1 = 0.f, ay1 = 0.f;
    int i = start;
    for (; i + 1 < end; i += 2) {
      unsigned w0 = h2[(size_t)adj[i] * 64 + lane];
      unsigned w1 = h2[(size_t)adj[i + 1] * 64 + lane];
      ax0 += bl(w0); ay0 += bh(w0);
      ax1 += bl(w1); ay1 += bh(w1);
    }
    if (i < end) {
      unsigned w0 = h2[(size_t)adj[i] * 64 + lane];
      ax0 += bl(w0); ay0 += bh(w0);
    }
    float r = rin[node];
    float ox = fmaf(ax0 + ax1, r, bias[lane * 2]);
    float oy = fmaf(ay0 + ay1, r, bias[lane * 2 + 1]);
    if (do_relu) { ox = fmaxf(ox, 0.f); oy = fmaxf(oy, 0.f); }
    ((unsigned*)hout)[(size_t)node * 64 + lane] = packbf2(ox, oy);
  } else {
    float a0 = 0.f, a1 = 0.f;
    int i = start;
    for (; i + 1 < end; i += 2) {
      unsigned short r0 = hin[(size_t)adj[i] * 64 + lane];
      unsigned short r1 = hin[(size_t)adj[i + 1] * 64 + lane];
      a0 += bl(r0); a1 += bl(r1);
    }
    if (i < end) a0 += bl(hin[(size_t)adj[i] * 64 + lane]);
    float o = fmaf(a0 + a1, rin[node], bias[lane]);
    if (do_relu) o = fmaxf(o, 0.f);
    hout[(size_t)node * 64 + lane] = f2bf(o);
  }
}

// per-edge MLP, CSR order, 128 edges/block.
// Phase 1: z1 bf16 tile [128][72] in LDS (gathers; dst side ~sequential).
// Phase 2: MFMA [128,64]@[64,32]; epilogue bp2+relu+Wp3 dot, 16-lane butterfly.
__global__ __launch_bounds__(256) void k_edge(
    const unsigned short* __restrict__ ab, const int* __restrict__ adj,
    const int* __restrict__ dnode, const int* __restrict__ eidx,
    const unsigned short* __restrict__ Wp2t, const float* __restrict__ bp1,
    const float* __restrict__ bp2, const float* __restrict__ Wp3,
    const float* __restrict__ bp3, float* __restrict__ out, int E) {
  __shared__ __attribute__((aligned(16))) unsigned short z1s[128][72];
  __shared__ __attribute__((aligned(16))) unsigned short w2t[32][72];
  __shared__ float sb1[64], sb2[32], sw3[32];

  int t = threadIdx.x;
  {
    // Wp2t: 32x64 shorts = 256 uint4 chunks, one per thread
    uint4 v = ((const uint4*)Wp2t)[t];
    int n = t >> 3, seg = t & 7;
    *(uint4*)&w2t[n][seg * 8] = v;
    if (t < 64) sb1[t] = bp1[t];
    else if (t < 96) sb2[t - 64] = bp2[t - 64];
    else if (t < 128) sw3[t - 96] = Wp3[t - 96];
  }
  __syncthreads();

  int p0 = blockIdx.x * 128;
  // phase 1: 2 threads/edge, 32 j's each
  {
    int m = t >> 1, half = t & 1, p = p0 + m;
    int s = 0, d = 0;
    if (p < E) { s = adj[p]; d = dnode[p]; }
    const uint4* apf = (const uint4*)(ab + (size_t)s * 128 + half * 32);
    const uint4* bpf = (const uint4*)(ab + (size_t)d * 128 + 64 + half * 32);
    int jb = half * 32;
#pragma unroll
    for (int q = 0; q < 4; q++) {
      uint4 av = apf[q], bv = bpf[q];
      int j = jb + 8 * q;
      float z0 = fmaxf(bl(av.x) + bl(bv.x) + sb1[j + 0], 0.f);
      float z1 = fmaxf(bh(av.x) + bh(bv.x) + sb1[j + 1], 0.f);
      float z2 = fmaxf(bl(av.y) + bl(bv.y) + sb1[j + 2], 0.f);
      float z3 = fmaxf(bh(av.y) + bh(bv.y) + sb1[j + 3], 0.f);
      float z4 = fmaxf(bl(av.z) + bl(bv.z) + sb1[j + 4], 0.f);
      float z5 = fmaxf(bh(av.z) + bh(bv.z) + sb1[j + 5], 0.f);
      float z6 = fmaxf(bl(av.w) + bl(bv.w) + sb1[j + 6], 0.f);
      float z7 = fmaxf(bh(av.w) + bh(bv.w) + sb1[j + 7], 0.f);
      uint4 o;
      o.x = packbf2(z0, z1); o.y = packbf2(z2, z3);
      o.z = packbf2(z4, z5); o.w = packbf2(z6, z7);
      *(uint4*)&z1s[m][j] = o;
    }
  }
  __syncthreads();

  // phase 2: wave handles 2 mtiles (32 edges); 2 ntiles, 2 ksteps
  int wav = t >> 6, lane = t & 63;
  int quad = lane >> 4, lrow = lane & 15;

  bf16x8 bfr[2][2];  // [s][nt]
#pragma unroll
  for (int s = 0; s < 2; s++)
#pragma unroll
    for (int nt = 0; nt < 2; nt++)
      bfr[s][nt] = *(const bf16x8*)&w2t[nt * 16 + lrow][s * 32 + quad * 8];

  f32x4 acc[2][2];
#pragma unroll
  for (int mt = 0; mt < 2; mt++)
#pragma unroll
    for (int nt = 0; nt < 2; nt++) acc[mt][nt] = (f32x4){0.f, 0.f, 0.f, 0.f};

#pragma unroll
  for (int mt = 0; mt < 2; mt++) {
    int mb = (wav * 2 + mt) * 16;
#pragma unroll
    for (int s = 0; s < 2; s++) {
      bf16x8 a = *(const bf16x8*)&z1s[mb + lrow][s * 32 + quad * 8];
#pragma unroll
      for (int nt = 0; nt < 2; nt++)
        acc[mt][nt] = __builtin_amdgcn_mfma_f32_16x16x32_bf16(a, bfr[s][nt], acc[mt][nt], 0, 0, 0);
    }
  }

  // epilogue: z2 = relu(acc + bp2), score partial = z2 . Wp3 (2 cols/lane)
  float bb0 = sb2[lrow], bb1 = sb2[16 + lrow];
  float w30 = sw3[lrow], w31 = sw3[16 + lrow];
  float p2[2][4];
#pragma unroll
  for (int mt = 0; mt < 2; mt++)
#pragma unroll
    for (int reg = 0; reg < 4; reg++)
      p2[mt][reg] = fmaxf(acc[mt][0][reg] + bb0, 0.f) * w30 +
                    fmaxf(acc[mt][1][reg] + bb1, 0.f) * w31;
#pragma unroll
  for (int off = 1; off < 16; off <<= 1) {
#pragma unroll
    for (int mt = 0; mt < 2; mt++)
#pragma unroll
      for (int reg = 0; reg < 4; reg++)
        p2[mt][reg] += __shfl_xor(p2[mt][reg], off, 64);
  }
  if (lrow < 4) {
    float b3 = bp3[0];
#pragma unroll
    for (int mt = 0; mt < 2; mt++) {
      float score = p2[mt][0];
      if (lrow == 1) score = p2[mt][1];
      if (lrow == 2) score = p2[mt][2];
      if (lrow == 3) score = p2[mt][3];
      score += b3;
      int pp = p0 + (wav * 2 + mt) * 16 + quad * 4 + lrow;
      if (pp < E) out[eidx[pp]] = 1.0f / (1.0f + __expf(-score));
    }
  }
}

extern "C" void kernel_launch(void* const* d_in, const int* in_sizes, int n_in,
                              void* d_out, int out_size, void* d_ws, size_t ws_size,
                              hipStream_t stream) {
  const float* x   = (const float*)d_in[0];
  const int*   src = (const int*)d_in[1];
  const int*   dst = (const int*)d_in[2];
  const float* W1  = (const float*)d_in[3];
  const float* b1  = (const float*)d_in[4];
  const float* W2  = (const float*)d_in[5];
  const float* b2  = (const float*)d_in[6];
  const float* Wp1 = (const float*)d_in[7];
  const float* bp1 = (const float*)d_in[8];
  const float* Wp2 = (const float*)d_in[9];
  const float* bp2 = (const float*)d_in[10];
  const float* Wp3 = (const float*)d_in[11];
  const float* bp3 = (const float*)d_in[12];
  float* out = (float*)d_out;

  int N = in_sizes[0] / 128;
  int E = in_sizes[1];

  char* w = (char*)d_ws;
  // bufA aliases pdst+sbuf (dead before first GEMM writes bufA)
  unsigned short* bufA = (unsigned short*)w;
  uint2* pdst = (uint2*)w;
  int*   sbuf = (int*)(w + (size_t)E * 8);
  w += (size_t)N * 128 * 2;
  unsigned short* bufB = (unsigned short*)w; w += (size_t)N * 128 * 2;
  int* grams  = (int*)w;    w += (size_t)GRT * sizeof(int);
  int* bsum   = (int*)w;    w += 256 * sizeof(int);
  int* rowst  = (int*)w;    w += (size_t)N * sizeof(int);
  int* adj    = (int*)w;    w += (size_t)E * sizeof(int);
  int* dnode  = (int*)w;    w += (size_t)E * sizeof(int);
  int* eidx   = (int*)w;    w += (size_t)E * sizeof(int);
  float* rin  = (float*)w;  w += (size_t)N * sizeof(float);
  float* rout = (float*)w;  w += (size_t)N * sizeof(float);
  unsigned short* W1t  = (unsigned short*)w; w += 16384 * 2;
  unsigned short* W2t  = (unsigned short*)w; w += 8192 * 2;
  unsigned short* Wct  = (unsigned short*)w; w += 8192 * 2;
  unsigned short* Wp2t = (unsigned short*)w; w += 2048 * 2;

  int nbk = (N + 255) / 256;

  // ---- CSR build (atomic-free counting sort) ----
  k_hist<<<NBLK, 256, 0, stream>>>(src, dst, grams, E);
  k_gscan1<<<GRT / 1024, 256, 0, stream>>>(grams, bsum);
  k_gscan3<<<GRT / 1024, 256, 0, stream>>>(grams, bsum);
  k_part<<<NBLK, 256, 0, stream>>>(src, dst, grams, pdst, sbuf, E);
  k_dcsr<<<nbk, 256, 0, stream>>>(pdst, grams, adj, dnode, eidx, rowst, rin, N);
  k_scsr<<<nbk, 256, 0, stream>>>(sbuf, grams, rout, N, E);
  k_prep<<<136, 256, 0, stream>>>(W1, W2, Wp1, Wp2, W1t, W2t, Wct, Wp2t);

  // ---- dense pipeline (MFMA bf16) ----
  // layer 1: h0 = bf16((x*rout) @ W1) -> bufA [N,128]
  k_gemm<128, 128, false, true><<<(N + 63) / 64, 256, 0, stream>>>(x, rout, W1t, bufA, N);
  // agg1 + bias + relu -> bufB [N,128] bf16
  k_agg<128><<<(N + 3) / 4, 256, 0, stream>>>(bufA, rowst, adj, rin, b1, bufB, N, E, 1);
  // layer 2: h2pre = bf16((h1*rout) @ W2) -> bufA [N,64]
  k_gemm<128, 64, true, true><<<(N + 63) / 64, 256, 0, stream>>>(bufB, rout, W2t, bufA, N);
  // agg2 + bias -> bufB [N,64] bf16
  k_agg<64><<<(N + 3) / 4, 256, 0, stream>>>(bufA, rowst, adj, rin, b2, bufB, N, E, 0);
  // predictor precompute: ab = bf16(h @ Wc) -> bufA [N,128]
  k_gemm<64, 128, true, false><<<(N + 63) / 64, 256, 0, stream>>>(bufB, nullptr, Wct, bufA, N);
  // edge MLP + sigmoid, CSR order, scatter by eidx -> out [E]
  k_edge<<<(E + 127) / 128, 256, 0, stream>>>(bufA, adj, dnode, eidx, Wp2t, bp1, bp2, Wp3, bp3, out, E);
}